// Round 2
// baseline (587.324 us; speedup 1.0000x reference)
//
#include <hip/hip_runtime.h>
#include <hip/hip_bf16.h>
#include <math.h>

typedef __attribute__((ext_vector_type(4))) float  float4v;
typedef __attribute__((ext_vector_type(2))) float  float2v;
typedef __attribute__((ext_vector_type(8))) short  short8;

#define B_ 8
#define L_ 384
#define H_ 128

__device__ __forceinline__ float bflo(unsigned int u){ unsigned int t = u << 16; float f; __builtin_memcpy(&f,&t,4); return f; }
__device__ __forceinline__ float bfhi(unsigned int u){ unsigned int t = u & 0xffff0000u; float f; __builtin_memcpy(&f,&t,4); return f; }
__device__ __forceinline__ unsigned short f2bf(float f){
  unsigned int t; __builtin_memcpy(&t,&f,4);
  return (unsigned short)((t + 0x7fffu + ((t>>16)&1u)) >> 16);
}
__device__ __forceinline__ float fsig(float x){ return __fdividef(1.f, 1.f + __expf(-x)); }
__device__ __forceinline__ float ftanh(float x){ return 1.f - __fdividef(2.f, __expf(2.f*x) + 1.f); }

// out[row][o] = act( in[row] . W[o][:] + bias[o] (+bias2[o]) )
// 32 rows x NT outs per WG. Weights staged transposed in LDS as bf16.
// inB != null  => input is concat(inA[:,0:128], inB[:,0:128]) with K==256.
// act==2: out = sigmoid(v) * in[row][ob+o]   (gating, requires Ntotal==K)
template<int K, int NT, int RPT>
__global__ __launch_bounds__(256) void rowgemm_kernel(
    const float* __restrict__ inA, const float* __restrict__ inB,
    const float* __restrict__ W, const float* __restrict__ bias,
    const float* __restrict__ bias2, float* __restrict__ out,
    int Ntotal, int act)
{
  constexpr int KP = K + 2;   // +2 u16 pad: conflict-free row broadcasts
  __shared__ __align__(16) unsigned short in_s[32*KP];
  __shared__ __align__(16) unsigned short wt_s[K*NT];
  const int tid  = threadIdx.x;
  const int row0 = blockIdx.x * 32;
  const int ob   = blockIdx.y * NT;

  // stage input rows f32 -> bf16
  #pragma unroll
  for (int it = 0; it < K/32; ++it) {
    int idx = it*256 + tid;
    int r = idx / (K/4);
    int k = (idx % (K/4)) * 4;
    float4v f;
    if (inB != nullptr && k >= 128)
      f = *(const float4v*)(inB + (size_t)(row0+r)*128 + (k-128));
    else if (inB != nullptr)
      f = *(const float4v*)(inA + (size_t)(row0+r)*128 + k);
    else
      f = *(const float4v*)(inA + (size_t)(row0+r)*K + k);
    unsigned int p0 = (unsigned int)f2bf(f.x) | ((unsigned int)f2bf(f.y) << 16);
    unsigned int p1 = (unsigned int)f2bf(f.z) | ((unsigned int)f2bf(f.w) << 16);
    *(unsigned int*)&in_s[r*KP + k]     = p0;
    *(unsigned int*)&in_s[r*KP + k + 2] = p1;
  }
  // stage weights transposed: wt_s[k*NT + o] = bf16(W[ob+o][k])
  #pragma unroll
  for (int it = 0; it < (NT*(K/4))/256; ++it) {
    int idx = it*256 + tid;
    int o = idx / (K/4);
    int k = (idx % (K/4)) * 4;
    float4v f = *(const float4v*)(W + (size_t)(ob+o)*K + k);
    wt_s[(k+0)*NT + o] = f2bf(f.x);
    wt_s[(k+1)*NT + o] = f2bf(f.y);
    wt_s[(k+2)*NT + o] = f2bf(f.z);
    wt_s[(k+3)*NT + o] = f2bf(f.w);
  }
  __syncthreads();

  constexpr int OG = NT/4;
  const int og = tid % OG;
  const int rg = tid / OG;
  const int o  = og * 4;
  float acc[RPT][4];
  #pragma unroll
  for (int i=0;i<RPT;++i){ acc[i][0]=0.f; acc[i][1]=0.f; acc[i][2]=0.f; acc[i][3]=0.f; }

  for (int kp = 0; kp < K/2; ++kp) {
    const int k = kp*2;
    uint2 wv0 = *(const uint2*)&wt_s[(k+0)*NT + o];
    uint2 wv1 = *(const uint2*)&wt_s[(k+1)*NT + o];
    float w00 = bflo(wv0.x), w01 = bfhi(wv0.x), w02 = bflo(wv0.y), w03 = bfhi(wv0.y);
    float w10 = bflo(wv1.x), w11 = bfhi(wv1.x), w12 = bflo(wv1.y), w13 = bfhi(wv1.y);
    #pragma unroll
    for (int i=0;i<RPT;++i) {
      unsigned int av = *(const unsigned int*)&in_s[(rg*RPT+i)*KP + k];
      float a0 = bflo(av), a1 = bfhi(av);
      acc[i][0] += a0*w00 + a1*w10;
      acc[i][1] += a0*w01 + a1*w11;
      acc[i][2] += a0*w02 + a1*w12;
      acc[i][3] += a0*w03 + a1*w13;
    }
  }

  float4v bv = *(const float4v*)(bias + ob + o);
  float b2v[4] = {0.f,0.f,0.f,0.f};
  if (bias2 != nullptr) {
    float4v t2 = *(const float4v*)(bias2 + ob + o);
    b2v[0]=t2.x; b2v[1]=t2.y; b2v[2]=t2.z; b2v[3]=t2.w;
  }
  #pragma unroll
  for (int i=0;i<RPT;++i) {
    const int r = rg*RPT + i;
    float4v ov;
    #pragma unroll
    for (int j=0;j<4;++j) {
      float val = acc[i][j] + bv[j] + b2v[j];
      if (act == 2) {
        float m = bflo((unsigned int)in_s[r*KP + ob + o + j]);
        val = fsig(val) * m;
      }
      ov[j] = val;
    }
    *(float4v*)(out + (size_t)(row0+r)*Ntotal + ob + o) = ov;
  }
}

// Fused additive attention: s[t,j] = V . tanh(xp[t]+yp[j]) + Vb, masked,
// online softmax over j, ct[t] = sum_j alpha_j * y[j].
// WG = 256 thr = 8 t-rows x 32 lanes; one (b, 8-t tile) per WG.
__global__ __launch_bounds__(256) void attn_kernel(
    const float* __restrict__ xp, const float* __restrict__ yp,
    const float* __restrict__ y, const unsigned char* __restrict__ xmask,
    const unsigned char* __restrict__ ymask, const float* __restrict__ Vw,
    const float* __restrict__ Vb, float* __restrict__ ct)
{
  __shared__ __align__(16) float xp_s[8][128];
  __shared__ __align__(16) float v_s[128];
  __shared__ __align__(16) float yp_s[32][130];
  __shared__ __align__(16) float yc_s[32][132];
  __shared__ float p_s[8][32];
  __shared__ float xm_s[8];
  __shared__ float ym_s[32];
  const int tid = threadIdx.x;
  const int b   = blockIdx.y;
  const int t0  = blockIdx.x * 8;
  {
    int r = tid >> 5, k4 = tid & 31;
    float4v f = *(const float4v*)(xp + ((size_t)(b*L_ + t0 + r))*H_ + k4*4);
    *(float4v*)&xp_s[r][k4*4] = f;
    if (tid < 32) { *(float4v*)&v_s[tid*4] = *(const float4v*)(Vw + tid*4); }
    if (tid < 8)  xm_s[tid] = xmask[b*L_ + t0 + tid] ? 0.f : 1.f;
  }
  const float vb = Vb[0];
  const int t = tid >> 5, u = tid & 31;
  float mrun = -__builtin_inff(), lrun = 0.f;
  float a0=0.f, a1=0.f, a2=0.f, a3=0.f;

  for (int c = 0; c < 12; ++c) {
    __syncthreads();
    // stage 32 rows x 128 cols of y_proj2 (pad 130) and y (pad 132):
    // 1024 float4 total -> 4 per thread (round-1 fix: was 1/4 coverage)
    #pragma unroll
    for (int it = 0; it < 4; ++it) {
      int idx = it*256 + tid;
      int r  = idx >> 5;          // 0..31
      int k4 = (idx & 31) * 4;    // 0..124
      size_t base = ((size_t)(b*L_ + c*32 + r))*H_ + k4;
      float4v fp = *(const float4v*)(yp + base);
      float2v* dp = (float2v*)&yp_s[r][k4];
      dp[0] = (float2v){fp.x, fp.y};
      dp[1] = (float2v){fp.z, fp.w};
      float4v fy = *(const float4v*)(y + base);
      *(float4v*)&yc_s[r][k4] = fy;
    }
    if (tid < 32) ym_s[tid] = ymask[b*L_ + c*32 + tid] ? 0.f : 1.f;
    __syncthreads();
    float s = 0.f;
    {
      const float* yr = yp_s[u];
      const float* xr = xp_s[t];
      #pragma unroll 8
      for (int k = 0; k < 128; k += 2) {
        float2v yv = *(const float2v*)&yr[k];
        float2v xv = *(const float2v*)&xr[k];
        float2v vv = *(const float2v*)&v_s[k];
        float t1 = xv[0] + yv[0];
        s += vv[0] * (1.f - __fdividef(2.f, __expf(2.f*t1) + 1.f));
        float t2 = xv[1] + yv[1];
        s += vv[1] * (1.f - __fdividef(2.f, __expf(2.f*t2) + 1.f));
      }
    }
    float ymv = ym_s[u];
    s = (s + vb) * xm_s[t] * ymv;
    if (ymv == 0.f) s = -__builtin_inff();
    // online softmax across the 32 lanes of row t
    float mc = s;
    #pragma unroll
    for (int off = 16; off >= 1; off >>= 1) mc = fmaxf(mc, __shfl_xor(mc, off));
    float mnew = fmaxf(mrun, mc);
    float p  = __expf(s - mnew);
    float sc = __expf(mrun - mnew);
    float ps = p;
    #pragma unroll
    for (int off = 16; off >= 1; off >>= 1) ps += __shfl_xor(ps, off);
    lrun = lrun * sc + ps;
    mrun = mnew;
    p_s[t][u] = p;
    __syncthreads();
    a0 *= sc; a1 *= sc; a2 *= sc; a3 *= sc;
    #pragma unroll 4
    for (int j = 0; j < 32; ++j) {
      float pv = p_s[t][j];
      float4v yv = *(const float4v*)&yc_s[j][u*4];
      a0 += pv*yv[0]; a1 += pv*yv[1]; a2 += pv*yv[2]; a3 += pv*yv[3];
    }
  }
  float inv = __fdividef(1.f, lrun);
  float4v ov; ov[0]=a0*inv; ov[1]=a1*inv; ov[2]=a2*inv; ov[3]=a3*inv;
  *(float4v*)(ct + ((size_t)(b*L_ + t0 + t))*H_ + u*4) = ov;
}

// LSTM scan: one WG per batch, 8 waves. W_hh resident in registers as bf16
// MFMA B-fragments. Wave w owns the 4 gate tiles (i,f,g,o) for hidden slice
// [16w,16w+16) so the c/h update is lane-local (quad 0 only). h double-
// buffered in LDS -> one barrier per step.
__global__ __launch_bounds__(512) void lstm_kernel(
    const float* __restrict__ gx, const float* __restrict__ Whh,
    const float* __restrict__ bhh, float* __restrict__ out)
{
  __shared__ __align__(16) unsigned short h_s[2][128];
  const int tid  = threadIdx.x;
  const int b    = blockIdx.x;
  const int w    = tid >> 6;
  const int l    = tid & 63;
  const int col  = l & 15;
  const int quad = l >> 4;

  // B fragment: lane holds B[k = kt*32+quad*8+j][n = nt*128 + w*16 + col] = Whh[n][k]
  short8 bf[4][4];
  #pragma unroll
  for (int nt = 0; nt < 4; ++nt) {
    const int n = nt*128 + w*16 + col;
    #pragma unroll
    for (int kt = 0; kt < 4; ++kt) {
      const int k0 = kt*32 + quad*8;
      const float* src = Whh + (size_t)n*H_ + k0;
      float4v f0 = *(const float4v*)(src);
      float4v f1 = *(const float4v*)(src + 4);
      short8 v;
      v[0]=(short)f2bf(f0[0]); v[1]=(short)f2bf(f0[1]); v[2]=(short)f2bf(f0[2]); v[3]=(short)f2bf(f0[3]);
      v[4]=(short)f2bf(f1[0]); v[5]=(short)f2bf(f1[1]); v[6]=(short)f2bf(f1[2]); v[7]=(short)f2bf(f1[3]);
      bf[nt][kt] = v;
    }
  }
  float bh[4];
  #pragma unroll
  for (int nt=0;nt<4;++nt) bh[nt] = bhh[nt*128 + w*16 + col];

  if (tid < 128) { h_s[0][tid] = 0; h_s[1][tid] = 0; }
  float cst = 0.f;
  const size_t grow = (size_t)b * L_ * 512;
  float gxv[4];
  #pragma unroll
  for (int nt=0;nt<4;++nt) gxv[nt] = gx[grow + nt*128 + w*16 + col];
  __syncthreads();

  for (int tstep = 0; tstep < L_; ++tstep) {
    const unsigned short* hb = h_s[tstep & 1];
    short8 a[4];
    #pragma unroll
    for (int kt=0;kt<4;++kt) a[kt] = *(const short8*)&hb[kt*32 + quad*8];
    float4v acc0 = {0.f,0.f,0.f,0.f};
    float4v acc1 = acc0, acc2 = acc0, acc3 = acc0;
    #pragma unroll
    for (int kt=0;kt<4;++kt) {
      acc0 = __builtin_amdgcn_mfma_f32_16x16x32_bf16(a[kt], bf[0][kt], acc0, 0,0,0);
      acc1 = __builtin_amdgcn_mfma_f32_16x16x32_bf16(a[kt], bf[1][kt], acc1, 0,0,0);
      acc2 = __builtin_amdgcn_mfma_f32_16x16x32_bf16(a[kt], bf[2][kt], acc2, 0,0,0);
      acc3 = __builtin_amdgcn_mfma_f32_16x16x32_bf16(a[kt], bf[3][kt], acc3, 0,0,0);
    }
    float g0 = acc0[0] + gxv[0] + bh[0];
    float g1 = acc1[0] + gxv[1] + bh[1];
    float g2 = acc2[0] + gxv[2] + bh[2];
    float g3 = acc3[0] + gxv[3] + bh[3];
    if (tstep + 1 < L_) {
      #pragma unroll
      for (int nt=0;nt<4;++nt)
        gxv[nt] = gx[grow + (size_t)(tstep+1)*512 + nt*128 + w*16 + col];
    }
    if (quad == 0) { // row 0 of C = the real (M=1) result
      float ig = fsig(g0), fg = fsig(g1), gg = ftanh(g2), og = fsig(g3);
      cst = fg*cst + ig*gg;
      float hn = og * ftanh(cst);
      out[((size_t)(b*L_ + tstep))*H_ + w*16 + col] = hn;
      h_s[(tstep+1)&1][w*16 + col] = f2bf(hn);
    }
    __syncthreads();
  }
}

extern "C" void kernel_launch(void* const* d_in, const int* in_sizes, int n_in,
                              void* d_out, int out_size, void* d_ws, size_t ws_size,
                              hipStream_t stream)
{
  (void)in_sizes; (void)n_in; (void)out_size; (void)ws_size;
  const float* x     = (const float*)d_in[0];
  const unsigned char* xm = (const unsigned char*)d_in[1];
  const float* y     = (const float*)d_in[2];
  const unsigned char* ym = (const unsigned char*)d_in[3];
  const float* Wq_w  = (const float*)d_in[4];
  const float* Wq_b  = (const float*)d_in[5];
  const float* Wup_w = (const float*)d_in[6];
  const float* Wup_b = (const float*)d_in[7];
  /* d_in[8] = Wvp_w: unused (hidden state is zero -> only its bias matters) */
  const float* Wvp_b = (const float*)d_in[9];
  const float* V_w   = (const float*)d_in[10];
  const float* V_b   = (const float*)d_in[11];
  const float* Wg_w  = (const float*)d_in[12];
  const float* Wg_b  = (const float*)d_in[13];
  const float* W_ih  = (const float*)d_in[14];
  const float* W_hh  = (const float*)d_in[15];
  const float* b_ih  = (const float*)d_in[16];
  const float* b_hh  = (const float*)d_in[17];
  float* out = (float*)d_out;

  float* wsf   = (float*)d_ws;
  float* xp_ws = wsf;                  // [3072][128]
  float* yp_ws = xp_ws + 393216;       // [3072][128]
  float* ct_ws = yp_ws + 393216;       // [3072][128]
  float* li_ws = ct_ws + 393216;       // [3072][256]
  float* gx_ws = li_ws + 786432;       // [3072][512]

  // x_proj = x @ Wup.T + Wup_b
  rowgemm_kernel<128,128,4><<<dim3(96,1),256,0,stream>>>(x, nullptr, Wup_w, Wup_b, nullptr, xp_ws, 128, 0);
  // y_proj2 = y @ Wq.T + Wq_b + Wvp_b (hidden_proj folded in)
  rowgemm_kernel<128,128,4><<<dim3(96,1),256,0,stream>>>(y, nullptr, Wq_w, Wq_b, Wvp_b, yp_ws, 128, 0);
  // fused scores + softmax + ct
  attn_kernel<<<dim3(48,8),256,0,stream>>>(xp_ws, yp_ws, y, xm, ym, V_w, V_b, ct_ws);
  // lstm_in = sigmoid([x,ct] @ Wg.T + Wg_b) * [x,ct]
  rowgemm_kernel<256,64,2><<<dim3(96,4),256,0,stream>>>(x, ct_ws, Wg_w, Wg_b, nullptr, li_ws, 256, 2);
  // gates_x = lstm_in @ W_ih.T + b_ih
  rowgemm_kernel<256,64,2><<<dim3(96,8),256,0,stream>>>(li_ws, nullptr, W_ih, b_ih, nullptr, gx_ws, 512, 0);
  // sequential LSTM
  lstm_kernel<<<dim3(8),512,0,stream>>>(gx_ws, W_hh, b_hh, out);
}

// Round 4
// 511.549 us; speedup vs baseline: 1.1481x; 1.1481x over previous
//
#include <hip/hip_runtime.h>
#include <hip/hip_bf16.h>
#include <math.h>

typedef __attribute__((ext_vector_type(4))) float  float4v;
typedef __attribute__((ext_vector_type(2))) float  float2v;
typedef __attribute__((ext_vector_type(8))) short  short8;

#define B_ 8
#define L_ 384
#define H_ 128

__device__ __forceinline__ float bflo(unsigned int u){ unsigned int t = u << 16; float f; __builtin_memcpy(&f,&t,4); return f; }
__device__ __forceinline__ float bfhi(unsigned int u){ unsigned int t = u & 0xffff0000u; float f; __builtin_memcpy(&f,&t,4); return f; }
__device__ __forceinline__ unsigned short f2bf(float f){
  unsigned int t; __builtin_memcpy(&t,&f,4);
  return (unsigned short)((t + 0x7fffu + ((t>>16)&1u)) >> 16);
}
__device__ __forceinline__ float fsig(float x){ return __fdividef(1.f, 1.f + __expf(-x)); }
__device__ __forceinline__ float ftanh(float x){ return 1.f - __fdividef(2.f, __expf(2.f*x) + 1.f); }

// lgkm-only barrier: LDS ordering without draining in-flight global loads/stores
// (__syncthreads would emit s_waitcnt vmcnt(0) — the round-2 1590cy/step killer)
__device__ __forceinline__ void barrier_lds(){
  asm volatile("s_waitcnt lgkmcnt(0)\n\ts_barrier" ::: "memory");
}

// out[row][o] = act( in[row] . W[o][:] + bias[o] (+bias2[o]) )
template<int K, int NT, int RPT>
__global__ __launch_bounds__(256) void rowgemm_kernel(
    const float* __restrict__ inA, const float* __restrict__ inB,
    const float* __restrict__ W, const float* __restrict__ bias,
    const float* __restrict__ bias2, float* __restrict__ out,
    int Ntotal, int act)
{
  constexpr int KP = K + 2;
  __shared__ __align__(16) unsigned short in_s[32*KP];
  __shared__ __align__(16) unsigned short wt_s[K*NT];
  const int tid  = threadIdx.x;
  const int row0 = blockIdx.x * 32;
  const int ob   = blockIdx.y * NT;

  #pragma unroll
  for (int it = 0; it < K/32; ++it) {
    int idx = it*256 + tid;
    int r = idx / (K/4);
    int k = (idx % (K/4)) * 4;
    float4v f;
    if (inB != nullptr && k >= 128)
      f = *(const float4v*)(inB + (size_t)(row0+r)*128 + (k-128));
    else if (inB != nullptr)
      f = *(const float4v*)(inA + (size_t)(row0+r)*128 + k);
    else
      f = *(const float4v*)(inA + (size_t)(row0+r)*K + k);
    unsigned int p0 = (unsigned int)f2bf(f.x) | ((unsigned int)f2bf(f.y) << 16);
    unsigned int p1 = (unsigned int)f2bf(f.z) | ((unsigned int)f2bf(f.w) << 16);
    *(unsigned int*)&in_s[r*KP + k]     = p0;
    *(unsigned int*)&in_s[r*KP + k + 2] = p1;
  }
  #pragma unroll
  for (int it = 0; it < (NT*(K/4))/256; ++it) {
    int idx = it*256 + tid;
    int o = idx / (K/4);
    int k = (idx % (K/4)) * 4;
    float4v f = *(const float4v*)(W + (size_t)(ob+o)*K + k);
    wt_s[(k+0)*NT + o] = f2bf(f.x);
    wt_s[(k+1)*NT + o] = f2bf(f.y);
    wt_s[(k+2)*NT + o] = f2bf(f.z);
    wt_s[(k+3)*NT + o] = f2bf(f.w);
  }
  __syncthreads();

  constexpr int OG = NT/4;
  const int og = tid % OG;
  const int rg = tid / OG;
  const int o  = og * 4;
  float acc[RPT][4];
  #pragma unroll
  for (int i=0;i<RPT;++i){ acc[i][0]=0.f; acc[i][1]=0.f; acc[i][2]=0.f; acc[i][3]=0.f; }

  for (int kp = 0; kp < K/2; ++kp) {
    const int k = kp*2;
    uint2 wv0 = *(const uint2*)&wt_s[(k+0)*NT + o];
    uint2 wv1 = *(const uint2*)&wt_s[(k+1)*NT + o];
    float w00 = bflo(wv0.x), w01 = bfhi(wv0.x), w02 = bflo(wv0.y), w03 = bfhi(wv0.y);
    float w10 = bflo(wv1.x), w11 = bfhi(wv1.x), w12 = bflo(wv1.y), w13 = bfhi(wv1.y);
    #pragma unroll
    for (int i=0;i<RPT;++i) {
      unsigned int av = *(const unsigned int*)&in_s[(rg*RPT+i)*KP + k];
      float a0 = bflo(av), a1 = bfhi(av);
      acc[i][0] += a0*w00 + a1*w10;
      acc[i][1] += a0*w01 + a1*w11;
      acc[i][2] += a0*w02 + a1*w12;
      acc[i][3] += a0*w03 + a1*w13;
    }
  }

  float4v bv = *(const float4v*)(bias + ob + o);
  float b2v[4] = {0.f,0.f,0.f,0.f};
  if (bias2 != nullptr) {
    float4v t2 = *(const float4v*)(bias2 + ob + o);
    b2v[0]=t2.x; b2v[1]=t2.y; b2v[2]=t2.z; b2v[3]=t2.w;
  }
  #pragma unroll
  for (int i=0;i<RPT;++i) {
    const int r = rg*RPT + i;
    float4v ov;
    #pragma unroll
    for (int j=0;j<4;++j) {
      float val = acc[i][j] + bv[j] + b2v[j];
      if (act == 2) {
        float m = bflo((unsigned int)in_s[r*KP + ob + o + j]);
        val = fsig(val) * m;
      }
      ov[j] = val;
    }
    *(float4v*)(out + (size_t)(row0+r)*Ntotal + ob + o) = ov;
  }
}

// Fused additive attention:
//  - score = svc - sum_k 2V[k] * rcp(exp2(C2*(x+y)) + 1)   (3 VALU + 2 trans/elem)
//  - chunk staging software-pipelined through registers
//  - p broadcast via __shfl width=32 (no 3rd barrier)
__global__ __launch_bounds__(256) void attn_kernel(
    const float* __restrict__ xp, const float* __restrict__ yp,
    const float* __restrict__ y, const unsigned char* __restrict__ xmask,
    const unsigned char* __restrict__ ymask, const float* __restrict__ Vw,
    const float* __restrict__ Vb, float* __restrict__ ct)
{
  __shared__ __align__(16) float xp_s[8][128];
  __shared__ __align__(16) float v2_s[128];
  __shared__ __align__(16) float yp_s[32][132];
  __shared__ __align__(16) float yc_s[32][132];
  __shared__ float xm_s[8];
  __shared__ float ym_s[32];
  __shared__ float sv_s;
  const int tid = threadIdx.x;
  const int b   = blockIdx.y;
  const int t0  = blockIdx.x * 8;
  const float C2 = 2.8853900817779268f;   // 2*log2(e)
  {
    int r = tid >> 5, k4 = (tid & 31) * 4;
    float4v f = *(const float4v*)(xp + ((size_t)(b*L_ + t0 + r))*H_ + k4);
    float4v g; g[0]=f[0]*C2; g[1]=f[1]*C2; g[2]=f[2]*C2; g[3]=f[3]*C2;
    *(float4v*)&xp_s[r][k4] = g;
    if (tid < 32) {
      float4v v = *(const float4v*)(Vw + tid*4);
      float4v v2; v2[0]=2.f*v[0]; v2[1]=2.f*v[1]; v2[2]=2.f*v[2]; v2[3]=2.f*v[3];
      *(float4v*)&v2_s[tid*4] = v2;
    }
    if (tid < 8) xm_s[tid] = xmask[b*L_ + t0 + tid] ? 0.f : 1.f;
  }
  __syncthreads();
  if (tid < 32) {      // svc = sum(V) + Vb, computed once
    float4v v = *(const float4v*)&v2_s[tid*4];
    float sm = (v[0]+v[1]) + (v[2]+v[3]);
    #pragma unroll
    for (int off = 16; off >= 1; off >>= 1) sm += __shfl_xor(sm, off);
    if (tid == 0) sv_s = 0.5f*sm + Vb[0];
  }

  float4v rp[4], ry[4];
  unsigned char ymb = 0;
  // prefetch chunk 0
  {
    #pragma unroll
    for (int it = 0; it < 4; ++it) {
      int idx = it*256 + tid; int r = idx >> 5; int k4 = (idx & 31) * 4;
      size_t base = ((size_t)(b*L_ + r))*H_ + k4;
      rp[it] = *(const float4v*)(yp + base);
      ry[it] = *(const float4v*)(y + base);
    }
    if (tid < 32) ymb = ymask[b*L_ + tid];
  }

  const int t = tid >> 5, u = tid & 31;
  float mrun = -__builtin_inff(), lrun = 0.f;
  float a0=0.f, a1=0.f, a2=0.f, a3=0.f;
  float svc = 0.f, xmv = 0.f;

  for (int c = 0; c < 12; ++c) {
    __syncthreads();   // LDS free; prefetch loads from last iter long since landed
    #pragma unroll
    for (int it = 0; it < 4; ++it) {
      int idx = it*256 + tid; int r = idx >> 5; int k4 = (idx & 31) * 4;
      float4v sp; sp[0]=rp[it][0]*C2; sp[1]=rp[it][1]*C2; sp[2]=rp[it][2]*C2; sp[3]=rp[it][3]*C2;
      *(float4v*)&yp_s[r][k4] = sp;
      *(float4v*)&yc_s[r][k4] = ry[it];
    }
    if (tid < 32) ym_s[tid] = ymb ? 0.f : 1.f;
    __syncthreads();   // staged
    if (c == 0) { svc = sv_s; xmv = xm_s[t]; }
    if (c < 11) { // prefetch next chunk AFTER the barrier: a full compute phase to land
      #pragma unroll
      for (int it = 0; it < 4; ++it) {
        int idx = it*256 + tid; int r = idx >> 5; int k4 = (idx & 31) * 4;
        size_t base = ((size_t)(b*L_ + (c+1)*32 + r))*H_ + k4;
        rp[it] = *(const float4v*)(yp + base);
        ry[it] = *(const float4v*)(y + base);
      }
      if (tid < 32) ymb = ymask[b*L_ + (c+1)*32 + tid];
    }

    float sA = 0.f, sB = 0.f;
    {
      const float* yr = yp_s[u];
      const float* xr = xp_s[t];
      #pragma unroll 4
      for (int k = 0; k < 128; k += 4) {
        float4v yv = *(const float4v*)&yr[k];
        float4v xv = *(const float4v*)&xr[k];
        float4v vv = *(const float4v*)&v2_s[k];
        float e0 = __builtin_amdgcn_exp2f(xv[0] + yv[0]);
        sA -= vv[0] * __builtin_amdgcn_rcpf(e0 + 1.f);
        float e1 = __builtin_amdgcn_exp2f(xv[1] + yv[1]);
        sB -= vv[1] * __builtin_amdgcn_rcpf(e1 + 1.f);
        float e2 = __builtin_amdgcn_exp2f(xv[2] + yv[2]);
        sA -= vv[2] * __builtin_amdgcn_rcpf(e2 + 1.f);
        float e3 = __builtin_amdgcn_exp2f(xv[3] + yv[3]);
        sB -= vv[3] * __builtin_amdgcn_rcpf(e3 + 1.f);
      }
    }
    float ymv = ym_s[u];
    float s = (svc + sA + sB) * xmv * ymv;
    if (ymv == 0.f) s = -__builtin_inff();
    // online softmax across the 32 lanes of row t
    float mc = s;
    #pragma unroll
    for (int off = 16; off >= 1; off >>= 1) mc = fmaxf(mc, __shfl_xor(mc, off));
    float mnew = fmaxf(mrun, mc);
    float p  = __expf(s - mnew);
    float sc = __expf(mrun - mnew);
    float ps = p;
    #pragma unroll
    for (int off = 16; off >= 1; off >>= 1) ps += __shfl_xor(ps, off);
    lrun = lrun * sc + ps;
    mrun = mnew;
    a0 *= sc; a1 *= sc; a2 *= sc; a3 *= sc;
    #pragma unroll 8
    for (int j = 0; j < 32; ++j) {
      float pv = __shfl(p, j, 32);   // broadcast within the 32-lane row group
      float4v yv = *(const float4v*)&yc_s[j][u*4];
      a0 += pv*yv[0]; a1 += pv*yv[1]; a2 += pv*yv[2]; a3 += pv*yv[3];
    }
  }
  float inv = __fdividef(1.f, lrun);
  float4v ov; ov[0]=a0*inv; ov[1]=a1*inv; ov[2]=a2*inv; ov[3]=a3*inv;
  *(float4v*)(ct + ((size_t)(b*L_ + t0 + t))*H_ + u*4) = ov;
}

// LSTM scan: lgkm-only barrier (gx prefetch + out stores stay in flight),
// 16 independent MFMAs, 4-deep gx register prefetch.
__global__ __launch_bounds__(512) void lstm_kernel(
    const float* __restrict__ gx, const float* __restrict__ Whh,
    const float* __restrict__ bhh, float* __restrict__ out)
{
  __shared__ __align__(16) unsigned short h_s[2][128];
  const int tid  = threadIdx.x;
  const int b    = blockIdx.x;
  const int w    = tid >> 6;
  const int l    = tid & 63;
  const int col  = l & 15;
  const int quad = l >> 4;

  short8 bf[4][4];
  #pragma unroll
  for (int nt = 0; nt < 4; ++nt) {
    const int n = nt*128 + w*16 + col;
    #pragma unroll
    for (int kt = 0; kt < 4; ++kt) {
      const int k0 = kt*32 + quad*8;
      const float* src = Whh + (size_t)n*H_ + k0;
      float4v f0 = *(const float4v*)(src);
      float4v f1 = *(const float4v*)(src + 4);
      short8 v;
      v[0]=(short)f2bf(f0[0]); v[1]=(short)f2bf(f0[1]); v[2]=(short)f2bf(f0[2]); v[3]=(short)f2bf(f0[3]);
      v[4]=(short)f2bf(f1[0]); v[5]=(short)f2bf(f1[1]); v[6]=(short)f2bf(f1[2]); v[7]=(short)f2bf(f1[3]);
      bf[nt][kt] = v;
    }
  }
  float bh[4];
  #pragma unroll
  for (int nt=0;nt<4;++nt) bh[nt] = bhh[nt*128 + w*16 + col];

  if (tid < 128) { h_s[0][tid] = 0; h_s[1][tid] = 0; }
  float cst = 0.f;
  const size_t grow = (size_t)b * L_ * 512;
  const int goff = w*16 + col;
  float gbuf[4][4];   // [slot][nt] — 4-step prefetch depth
  #pragma unroll
  for (int s = 0; s < 4; ++s)
    #pragma unroll
    for (int nt = 0; nt < 4; ++nt)
      gbuf[s][nt] = gx[grow + (size_t)s*512 + nt*128 + goff];
  __syncthreads();

  for (int t4 = 0; t4 < L_; t4 += 4) {
    #pragma unroll
    for (int s = 0; s < 4; ++s) {
      const int tstep = t4 + s;
      const unsigned short* hb = h_s[s & 1];
      short8 a[4];
      #pragma unroll
      for (int kt=0;kt<4;++kt) a[kt] = *(const short8*)&hb[kt*32 + quad*8];
      float4v acc[4][4];
      #pragma unroll
      for (int nt=0;nt<4;++nt)
        #pragma unroll
        for (int kt=0;kt<4;++kt) {
          float4v z = {0.f,0.f,0.f,0.f};
          acc[nt][kt] = __builtin_amdgcn_mfma_f32_16x16x32_bf16(a[kt], bf[nt][kt], z, 0,0,0);
        }
      float g[4];
      #pragma unroll
      for (int nt=0;nt<4;++nt)
        g[nt] = ((acc[nt][0][0] + acc[nt][1][0]) + (acc[nt][2][0] + acc[nt][3][0]))
                + gbuf[s][nt] + bh[nt];
      if (tstep + 4 < L_) {   // refill this slot, 4 steps ahead
        #pragma unroll
        for (int nt=0;nt<4;++nt)
          gbuf[s][nt] = gx[grow + (size_t)(tstep+4)*512 + nt*128 + goff];
      }
      if (quad == 0) {
        float ig = fsig(g[0]), fg = fsig(g[1]), gg = ftanh(g[2]), og = fsig(g[3]);
        cst = fg*cst + ig*gg;
        float hn = og * ftanh(cst);
        out[((size_t)(b*L_ + tstep))*H_ + w*16 + col] = hn;
        h_s[(s+1)&1][w*16 + col] = f2bf(hn);
      }
      barrier_lds();
    }
  }
}

extern "C" void kernel_launch(void* const* d_in, const int* in_sizes, int n_in,
                              void* d_out, int out_size, void* d_ws, size_t ws_size,
                              hipStream_t stream)
{
  (void)in_sizes; (void)n_in; (void)out_size; (void)ws_size;
  const float* x     = (const float*)d_in[0];
  const unsigned char* xm = (const unsigned char*)d_in[1];
  const float* y     = (const float*)d_in[2];
  const unsigned char* ym = (const unsigned char*)d_in[3];
  const float* Wq_w  = (const float*)d_in[4];
  const float* Wq_b  = (const float*)d_in[5];
  const float* Wup_w = (const float*)d_in[6];
  const float* Wup_b = (const float*)d_in[7];
  const float* Wvp_b = (const float*)d_in[9];
  const float* V_w   = (const float*)d_in[10];
  const float* V_b   = (const float*)d_in[11];
  const float* Wg_w  = (const float*)d_in[12];
  const float* Wg_b  = (const float*)d_in[13];
  const float* W_ih  = (const float*)d_in[14];
  const float* W_hh  = (const float*)d_in[15];
  const float* b_ih  = (const float*)d_in[16];
  const float* b_hh  = (const float*)d_in[17];
  float* out = (float*)d_out;

  float* wsf   = (float*)d_ws;
  float* xp_ws = wsf;                  // [3072][128]
  float* yp_ws = xp_ws + 393216;       // [3072][128]
  float* ct_ws = yp_ws + 393216;       // [3072][128]
  float* li_ws = ct_ws + 393216;       // [3072][256]
  float* gx_ws = li_ws + 786432;       // [3072][512]

  rowgemm_kernel<128,128,4><<<dim3(96,1),256,0,stream>>>(x, nullptr, Wup_w, Wup_b, nullptr, xp_ws, 128, 0);
  rowgemm_kernel<128,128,4><<<dim3(96,1),256,0,stream>>>(y, nullptr, Wq_w, Wq_b, Wvp_b, yp_ws, 128, 0);
  attn_kernel<<<dim3(48,8),256,0,stream>>>(xp_ws, yp_ws, y, xm, ym, V_w, V_b, ct_ws);
  rowgemm_kernel<256,64,2><<<dim3(96,4),256,0,stream>>>(x, ct_ws, Wg_w, Wg_b, nullptr, li_ws, 256, 2);
  rowgemm_kernel<256,64,2><<<dim3(96,8),256,0,stream>>>(li_ws, nullptr, W_ih, b_ih, nullptr, gx_ws, 512, 0);
  lstm_kernel<<<dim3(8),512,0,stream>>>(gx_ws, W_hh, b_hh, out);
}

// Round 5
// 446.618 us; speedup vs baseline: 1.3150x; 1.1454x over previous
//
#include <hip/hip_runtime.h>
#include <hip/hip_bf16.h>
#include <math.h>

typedef __attribute__((ext_vector_type(4))) float  float4v;
typedef __attribute__((ext_vector_type(2))) float  float2v;
typedef __attribute__((ext_vector_type(8))) short  short8;

#define B_ 8
#define L_ 384
#define H_ 128

__device__ __forceinline__ float bflo(unsigned int u){ unsigned int t = u << 16; float f; __builtin_memcpy(&f,&t,4); return f; }
__device__ __forceinline__ float bfhi(unsigned int u){ unsigned int t = u & 0xffff0000u; float f; __builtin_memcpy(&f,&t,4); return f; }
__device__ __forceinline__ unsigned short f2bf(float f){
  unsigned int t; __builtin_memcpy(&t,&f,4);
  return (unsigned short)((t + 0x7fffu + ((t>>16)&1u)) >> 16);
}
__device__ __forceinline__ float fsig(float x){ return __fdividef(1.f, 1.f + __expf(-x)); }

// lgkm-only barrier: LDS ordering without draining in-flight global loads/stores
__device__ __forceinline__ void barrier_lds(){
  asm volatile("s_waitcnt lgkmcnt(0)\n\ts_barrier" ::: "memory");
}

// out[row][o] = act( in[row] . W[o][:] + bias[o] (+bias2[o]) )
// act==2: out = sigmoid(v) * in[row][ob+o]   (gating, requires Ntotal==K)
// act==3: gate-interleaved store: out[row*512 + h*4 + nt], oo = nt*128+h
template<int K, int NT, int RPT>
__global__ __launch_bounds__(256) void rowgemm_kernel(
    const float* __restrict__ inA, const float* __restrict__ inB,
    const float* __restrict__ W, const float* __restrict__ bias,
    const float* __restrict__ bias2, float* __restrict__ out,
    int Ntotal, int act)
{
  constexpr int KP = K + 2;
  __shared__ __align__(16) unsigned short in_s[32*KP];
  __shared__ __align__(16) unsigned short wt_s[K*NT];
  const int tid  = threadIdx.x;
  const int row0 = blockIdx.x * 32;
  const int ob   = blockIdx.y * NT;

  #pragma unroll
  for (int it = 0; it < K/32; ++it) {
    int idx = it*256 + tid;
    int r = idx / (K/4);
    int k = (idx % (K/4)) * 4;
    float4v f;
    if (inB != nullptr && k >= 128)
      f = *(const float4v*)(inB + (size_t)(row0+r)*128 + (k-128));
    else if (inB != nullptr)
      f = *(const float4v*)(inA + (size_t)(row0+r)*128 + k);
    else
      f = *(const float4v*)(inA + (size_t)(row0+r)*K + k);
    unsigned int p0 = (unsigned int)f2bf(f.x) | ((unsigned int)f2bf(f.y) << 16);
    unsigned int p1 = (unsigned int)f2bf(f.z) | ((unsigned int)f2bf(f.w) << 16);
    *(unsigned int*)&in_s[r*KP + k]     = p0;
    *(unsigned int*)&in_s[r*KP + k + 2] = p1;
  }
  #pragma unroll
  for (int it = 0; it < (NT*(K/4))/256; ++it) {
    int idx = it*256 + tid;
    int o = idx / (K/4);
    int k = (idx % (K/4)) * 4;
    float4v f = *(const float4v*)(W + (size_t)(ob+o)*K + k);
    wt_s[(k+0)*NT + o] = f2bf(f.x);
    wt_s[(k+1)*NT + o] = f2bf(f.y);
    wt_s[(k+2)*NT + o] = f2bf(f.z);
    wt_s[(k+3)*NT + o] = f2bf(f.w);
  }
  __syncthreads();

  constexpr int OG = NT/4;
  const int og = tid % OG;
  const int rg = tid / OG;
  const int o  = og * 4;
  float acc[RPT][4];
  #pragma unroll
  for (int i=0;i<RPT;++i){ acc[i][0]=0.f; acc[i][1]=0.f; acc[i][2]=0.f; acc[i][3]=0.f; }

  for (int kp = 0; kp < K/2; ++kp) {
    const int k = kp*2;
    uint2 wv0 = *(const uint2*)&wt_s[(k+0)*NT + o];
    uint2 wv1 = *(const uint2*)&wt_s[(k+1)*NT + o];
    float w00 = bflo(wv0.x), w01 = bfhi(wv0.x), w02 = bflo(wv0.y), w03 = bfhi(wv0.y);
    float w10 = bflo(wv1.x), w11 = bfhi(wv1.x), w12 = bflo(wv1.y), w13 = bfhi(wv1.y);
    #pragma unroll
    for (int i=0;i<RPT;++i) {
      unsigned int av = *(const unsigned int*)&in_s[(rg*RPT+i)*KP + k];
      float a0 = bflo(av), a1 = bfhi(av);
      acc[i][0] += a0*w00 + a1*w10;
      acc[i][1] += a0*w01 + a1*w11;
      acc[i][2] += a0*w02 + a1*w12;
      acc[i][3] += a0*w03 + a1*w13;
    }
  }

  float4v bv = *(const float4v*)(bias + ob + o);
  float b2v[4] = {0.f,0.f,0.f,0.f};
  if (bias2 != nullptr) {
    float4v t2 = *(const float4v*)(bias2 + ob + o);
    b2v[0]=t2.x; b2v[1]=t2.y; b2v[2]=t2.z; b2v[3]=t2.w;
  }
  #pragma unroll
  for (int i=0;i<RPT;++i) {
    const int r = rg*RPT + i;
    float4v ov;
    #pragma unroll
    for (int j=0;j<4;++j) {
      float val = acc[i][j] + bv[j] + b2v[j];
      if (act == 2) {
        float m = bflo((unsigned int)in_s[r*KP + ob + o + j]);
        val = fsig(val) * m;
      }
      ov[j] = val;
    }
    if (act == 3) {
      #pragma unroll
      for (int j=0;j<4;++j) {
        int oo = ob + o + j;
        out[(size_t)(row0+r)*Ntotal + (oo & 127)*4 + (oo >> 7)] = ov[j];
      }
    } else {
      *(float4v*)(out + (size_t)(row0+r)*Ntotal + ob + o) = ov;
    }
  }
}

// Fused additive attention (unchanged from round 4)
__global__ __launch_bounds__(256) void attn_kernel(
    const float* __restrict__ xp, const float* __restrict__ yp,
    const float* __restrict__ y, const unsigned char* __restrict__ xmask,
    const unsigned char* __restrict__ ymask, const float* __restrict__ Vw,
    const float* __restrict__ Vb, float* __restrict__ ct)
{
  __shared__ __align__(16) float xp_s[8][128];
  __shared__ __align__(16) float v2_s[128];
  __shared__ __align__(16) float yp_s[32][132];
  __shared__ __align__(16) float yc_s[32][132];
  __shared__ float xm_s[8];
  __shared__ float ym_s[32];
  __shared__ float sv_s;
  const int tid = threadIdx.x;
  const int b   = blockIdx.y;
  const int t0  = blockIdx.x * 8;
  const float C2 = 2.8853900817779268f;   // 2*log2(e)
  {
    int r = tid >> 5, k4 = (tid & 31) * 4;
    float4v f = *(const float4v*)(xp + ((size_t)(b*L_ + t0 + r))*H_ + k4);
    float4v g; g[0]=f[0]*C2; g[1]=f[1]*C2; g[2]=f[2]*C2; g[3]=f[3]*C2;
    *(float4v*)&xp_s[r][k4] = g;
    if (tid < 32) {
      float4v v = *(const float4v*)(Vw + tid*4);
      float4v v2; v2[0]=2.f*v[0]; v2[1]=2.f*v[1]; v2[2]=2.f*v[2]; v2[3]=2.f*v[3];
      *(float4v*)&v2_s[tid*4] = v2;
    }
    if (tid < 8) xm_s[tid] = xmask[b*L_ + t0 + tid] ? 0.f : 1.f;
  }
  __syncthreads();
  if (tid < 32) {
    float4v v = *(const float4v*)&v2_s[tid*4];
    float sm = (v[0]+v[1]) + (v[2]+v[3]);
    #pragma unroll
    for (int off = 16; off >= 1; off >>= 1) sm += __shfl_xor(sm, off);
    if (tid == 0) sv_s = 0.5f*sm + Vb[0];
  }

  float4v rp[4], ry[4];
  unsigned char ymb = 0;
  {
    #pragma unroll
    for (int it = 0; it < 4; ++it) {
      int idx = it*256 + tid; int r = idx >> 5; int k4 = (idx & 31) * 4;
      size_t base = ((size_t)(b*L_ + r))*H_ + k4;
      rp[it] = *(const float4v*)(yp + base);
      ry[it] = *(const float4v*)(y + base);
    }
    if (tid < 32) ymb = ymask[b*L_ + tid];
  }

  const int t = tid >> 5, u = tid & 31;
  float mrun = -__builtin_inff(), lrun = 0.f;
  float a0=0.f, a1=0.f, a2=0.f, a3=0.f;
  float svc = 0.f, xmv = 0.f;

  for (int c = 0; c < 12; ++c) {
    __syncthreads();
    #pragma unroll
    for (int it = 0; it < 4; ++it) {
      int idx = it*256 + tid; int r = idx >> 5; int k4 = (idx & 31) * 4;
      float4v sp; sp[0]=rp[it][0]*C2; sp[1]=rp[it][1]*C2; sp[2]=rp[it][2]*C2; sp[3]=rp[it][3]*C2;
      *(float4v*)&yp_s[r][k4] = sp;
      *(float4v*)&yc_s[r][k4] = ry[it];
    }
    if (tid < 32) ym_s[tid] = ymb ? 0.f : 1.f;
    __syncthreads();
    if (c == 0) { svc = sv_s; xmv = xm_s[t]; }
    if (c < 11) {
      #pragma unroll
      for (int it = 0; it < 4; ++it) {
        int idx = it*256 + tid; int r = idx >> 5; int k4 = (idx & 31) * 4;
        size_t base = ((size_t)(b*L_ + (c+1)*32 + r))*H_ + k4;
        rp[it] = *(const float4v*)(yp + base);
        ry[it] = *(const float4v*)(y + base);
      }
      if (tid < 32) ymb = ymask[b*L_ + (c+1)*32 + tid];
    }

    float sA = 0.f, sB = 0.f;
    {
      const float* yr = yp_s[u];
      const float* xr = xp_s[t];
      #pragma unroll 4
      for (int k = 0; k < 128; k += 4) {
        float4v yv = *(const float4v*)&yr[k];
        float4v xv = *(const float4v*)&xr[k];
        float4v vv = *(const float4v*)&v2_s[k];
        float e0 = __builtin_amdgcn_exp2f(xv[0] + yv[0]);
        sA -= vv[0] * __builtin_amdgcn_rcpf(e0 + 1.f);
        float e1 = __builtin_amdgcn_exp2f(xv[1] + yv[1]);
        sB -= vv[1] * __builtin_amdgcn_rcpf(e1 + 1.f);
        float e2 = __builtin_amdgcn_exp2f(xv[2] + yv[2]);
        sA -= vv[2] * __builtin_amdgcn_rcpf(e2 + 1.f);
        float e3 = __builtin_amdgcn_exp2f(xv[3] + yv[3]);
        sB -= vv[3] * __builtin_amdgcn_rcpf(e3 + 1.f);
      }
    }
    float ymv = ym_s[u];
    float s = (svc + sA + sB) * xmv * ymv;
    if (ymv == 0.f) s = -__builtin_inff();
    float mc = s;
    #pragma unroll
    for (int off = 16; off >= 1; off >>= 1) mc = fmaxf(mc, __shfl_xor(mc, off));
    float mnew = fmaxf(mrun, mc);
    float p  = __expf(s - mnew);
    float sc = __expf(mrun - mnew);
    float ps = p;
    #pragma unroll
    for (int off = 16; off >= 1; off >>= 1) ps += __shfl_xor(ps, off);
    lrun = lrun * sc + ps;
    mrun = mnew;
    a0 *= sc; a1 *= sc; a2 *= sc; a3 *= sc;
    #pragma unroll 8
    for (int j = 0; j < 32; ++j) {
      float pv = __shfl(p, j, 32);
      float4v yv = *(const float4v*)&yc_s[j][u*4];
      a0 += pv*yv[0]; a1 += pv*yv[1]; a2 += pv*yv[2]; a3 += pv*yv[3];
    }
  }
  float inv = __fdividef(1.f, lrun);
  float4v ov; ov[0]=a0*inv; ov[1]=a1*inv; ov[2]=a2*inv; ov[3]=a3*inv;
  *(float4v*)(ct + ((size_t)(b*L_ + t0 + t))*H_ + u*4) = ov;
}

// LSTM scan, round-5: gate-interleaved gx (1 dwordx4/step), chained MFMA with
// hoisted zero C, b_hh pre-folded into gx, exp2/rcp gates, lgkm-only barrier.
__global__ __launch_bounds__(512) void lstm_kernel(
    const float* __restrict__ gx, const float* __restrict__ Whh,
    float* __restrict__ out)
{
  __shared__ __align__(16) unsigned short h_s[2][128];
  const int tid  = threadIdx.x;
  const int b    = blockIdx.x;
  const int w    = tid >> 6;
  const int l    = tid & 63;
  const int col  = l & 15;
  const int quad = l >> 4;

  short8 bf[4][4];
  #pragma unroll
  for (int nt = 0; nt < 4; ++nt) {
    const int n = nt*128 + w*16 + col;
    #pragma unroll
    for (int kt = 0; kt < 4; ++kt) {
      const int k0 = kt*32 + quad*8;
      const float* src = Whh + (size_t)n*H_ + k0;
      float4v f0 = *(const float4v*)(src);
      float4v f1 = *(const float4v*)(src + 4);
      short8 v;
      v[0]=(short)f2bf(f0[0]); v[1]=(short)f2bf(f0[1]); v[2]=(short)f2bf(f0[2]); v[3]=(short)f2bf(f0[3]);
      v[4]=(short)f2bf(f1[0]); v[5]=(short)f2bf(f1[1]); v[6]=(short)f2bf(f1[2]); v[7]=(short)f2bf(f1[3]);
      bf[nt][kt] = v;
    }
  }

  if (tid < 128) { h_s[0][tid] = 0; h_s[1][tid] = 0; }
  float cst = 0.f;
  const int goff = w*16 + col;                       // hidden index this lane owns
  const float* gbase = gx + (size_t)b*L_*512 + goff*4;  // gate-interleaved layout
  float* outp = out + (size_t)b*L_*H_ + goff;
  float4v gbuf[4];
  #pragma unroll
  for (int s = 0; s < 4; ++s)
    gbuf[s] = *(const float4v*)(gbase + (size_t)s*512);
  const float4v z4 = {0.f,0.f,0.f,0.f};
  const float NL2E = -1.4426950408889634f;   // -log2(e)
  const float P2L2E = 2.8853900817779268f;   //  2*log2(e)
  __syncthreads();

  for (int t4 = 0; t4 < L_; t4 += 4) {
    #pragma unroll
    for (int s = 0; s < 4; ++s) {
      const int tstep = t4 + s;
      const unsigned short* hb = h_s[s & 1];
      short8 a[4];
      #pragma unroll
      for (int kt=0;kt<4;++kt) a[kt] = *(const short8*)&hb[kt*32 + quad*8];
      // 4 independent depth-4 MFMA chains, C hoisted to a persistent zero
      float4v c0 = z4, c1 = z4, c2 = z4, c3 = z4;
      #pragma unroll
      for (int kt=0;kt<4;++kt) {
        c0 = __builtin_amdgcn_mfma_f32_16x16x32_bf16(a[kt], bf[0][kt], c0, 0,0,0);
        c1 = __builtin_amdgcn_mfma_f32_16x16x32_bf16(a[kt], bf[1][kt], c1, 0,0,0);
        c2 = __builtin_amdgcn_mfma_f32_16x16x32_bf16(a[kt], bf[2][kt], c2, 0,0,0);
        c3 = __builtin_amdgcn_mfma_f32_16x16x32_bf16(a[kt], bf[3][kt], c3, 0,0,0);
      }
      float g0 = c0[0] + gbuf[s][0];
      float g1 = c1[0] + gbuf[s][1];
      float g2 = c2[0] + gbuf[s][2];
      float g3 = c3[0] + gbuf[s][3];
      if (tstep + 4 < L_)
        gbuf[s] = *(const float4v*)(gbase + (size_t)(tstep+4)*512);
      if (quad == 0) {
        float ig = __builtin_amdgcn_rcpf(1.f + __builtin_amdgcn_exp2f(NL2E*g0));
        float fg = __builtin_amdgcn_rcpf(1.f + __builtin_amdgcn_exp2f(NL2E*g1));
        float gg = 1.f - 2.f*__builtin_amdgcn_rcpf(__builtin_amdgcn_exp2f(P2L2E*g2) + 1.f);
        float og = __builtin_amdgcn_rcpf(1.f + __builtin_amdgcn_exp2f(NL2E*g3));
        cst = fg*cst + ig*gg;
        float hn = og * (1.f - 2.f*__builtin_amdgcn_rcpf(__builtin_amdgcn_exp2f(P2L2E*cst) + 1.f));
        outp[(size_t)tstep*H_] = hn;
        h_s[(s+1)&1][goff] = f2bf(hn);
      }
      barrier_lds();
    }
  }
}

extern "C" void kernel_launch(void* const* d_in, const int* in_sizes, int n_in,
                              void* d_out, int out_size, void* d_ws, size_t ws_size,
                              hipStream_t stream)
{
  (void)in_sizes; (void)n_in; (void)out_size; (void)ws_size;
  const float* x     = (const float*)d_in[0];
  const unsigned char* xm = (const unsigned char*)d_in[1];
  const float* y     = (const float*)d_in[2];
  const unsigned char* ym = (const unsigned char*)d_in[3];
  const float* Wq_w  = (const float*)d_in[4];
  const float* Wq_b  = (const float*)d_in[5];
  const float* Wup_w = (const float*)d_in[6];
  const float* Wup_b = (const float*)d_in[7];
  const float* Wvp_b = (const float*)d_in[9];
  const float* V_w   = (const float*)d_in[10];
  const float* V_b   = (const float*)d_in[11];
  const float* Wg_w  = (const float*)d_in[12];
  const float* Wg_b  = (const float*)d_in[13];
  const float* W_ih  = (const float*)d_in[14];
  const float* W_hh  = (const float*)d_in[15];
  const float* b_ih  = (const float*)d_in[16];
  const float* b_hh  = (const float*)d_in[17];
  float* out = (float*)d_out;

  float* wsf   = (float*)d_ws;
  float* xp_ws = wsf;                  // [3072][128]
  float* yp_ws = xp_ws + 393216;       // [3072][128]
  float* ct_ws = yp_ws + 393216;       // [3072][128]
  float* li_ws = ct_ws + 393216;       // [3072][256]
  float* gx_ws = li_ws + 786432;       // [3072][512] gate-interleaved [t][h][4]

  rowgemm_kernel<128,128,4><<<dim3(96,1),256,0,stream>>>(x, nullptr, Wup_w, Wup_b, nullptr, xp_ws, 128, 0);
  rowgemm_kernel<128,128,4><<<dim3(96,1),256,0,stream>>>(y, nullptr, Wq_w, Wq_b, Wvp_b, yp_ws, 128, 0);
  attn_kernel<<<dim3(48,8),256,0,stream>>>(xp_ws, yp_ws, y, xm, ym, V_w, V_b, ct_ws);
  rowgemm_kernel<256,64,2><<<dim3(96,4),256,0,stream>>>(x, ct_ws, Wg_w, Wg_b, nullptr, li_ws, 256, 2);
  // gates_x = lstm_in @ W_ih.T + (b_ih + b_hh), stored gate-interleaved
  rowgemm_kernel<256,64,2><<<dim3(96,8),256,0,stream>>>(li_ws, nullptr, W_ih, b_ih, b_hh, gx_ws, 512, 3);
  lstm_kernel<<<dim3(8),512,0,stream>>>(gx_ws, W_hh, out);
}

// Round 6
// 413.164 us; speedup vs baseline: 1.4215x; 1.0810x over previous
//
#include <hip/hip_runtime.h>
#include <hip/hip_bf16.h>
#include <math.h>

typedef __attribute__((ext_vector_type(4))) float  float4v;
typedef __attribute__((ext_vector_type(2))) float  float2v;
typedef __attribute__((ext_vector_type(8))) short  short8;

#define B_ 8
#define L_ 384
#define H_ 128

__device__ __forceinline__ float bflo(unsigned int u){ unsigned int t = u << 16; float f; __builtin_memcpy(&f,&t,4); return f; }
__device__ __forceinline__ float bfhi(unsigned int u){ unsigned int t = u & 0xffff0000u; float f; __builtin_memcpy(&f,&t,4); return f; }
__device__ __forceinline__ unsigned short f2bf(float f){
  unsigned int t; __builtin_memcpy(&t,&f,4);
  return (unsigned short)((t + 0x7fffu + ((t>>16)&1u)) >> 16);
}
__device__ __forceinline__ float fsig(float x){ return __fdividef(1.f, 1.f + __expf(-x)); }

// lgkm-only barrier: LDS ordering without draining in-flight global loads/stores
__device__ __forceinline__ void barrier_lds(){
  asm volatile("s_waitcnt lgkmcnt(0)\n\ts_barrier" ::: "memory");
}

// out[row][o] = act( in[row] . W[o][:] + bias[o] (+bias2[o]) )
// act==2: out = sigmoid(v) * in[row][ob+o]   (gating, requires Ntotal==K)
// act==3: gate-interleaved store: out[row*512 + h*4 + nt], oo = nt*128+h
template<int K, int NT, int RPT>
__device__ __forceinline__ void rowgemm_body(
    unsigned short* in_s, unsigned short* wt_s,
    const float* __restrict__ inA, const float* __restrict__ inB,
    const float* __restrict__ W, const float* __restrict__ bias,
    const float* __restrict__ bias2, float* __restrict__ out,
    int Ntotal, int act, int row0, int ob)
{
  constexpr int KP = K + 2;
  const int tid = threadIdx.x;

  #pragma unroll
  for (int it = 0; it < K/32; ++it) {
    int idx = it*256 + tid;
    int r = idx / (K/4);
    int k = (idx % (K/4)) * 4;
    float4v f;
    if (inB != nullptr && k >= 128)
      f = *(const float4v*)(inB + (size_t)(row0+r)*128 + (k-128));
    else if (inB != nullptr)
      f = *(const float4v*)(inA + (size_t)(row0+r)*128 + k);
    else
      f = *(const float4v*)(inA + (size_t)(row0+r)*K + k);
    unsigned int p0 = (unsigned int)f2bf(f.x) | ((unsigned int)f2bf(f.y) << 16);
    unsigned int p1 = (unsigned int)f2bf(f.z) | ((unsigned int)f2bf(f.w) << 16);
    *(unsigned int*)&in_s[r*KP + k]     = p0;
    *(unsigned int*)&in_s[r*KP + k + 2] = p1;
  }
  // o-major weight staging: consecutive lanes -> consecutive o -> consecutive
  // banks (conflict-free LDS writes; round-5 layout was 32-way conflicted).
  // Global reads become K-strided 16B granules -> absorbed by L2/L3.
  #pragma unroll
  for (int it = 0; it < (NT*(K/4))/256; ++it) {
    int idx = it*256 + tid;
    int o = idx % NT;
    int k = (idx / NT) * 4;
    float4v f = *(const float4v*)(W + (size_t)(ob+o)*K + k);
    wt_s[(k+0)*NT + o] = f2bf(f.x);
    wt_s[(k+1)*NT + o] = f2bf(f.y);
    wt_s[(k+2)*NT + o] = f2bf(f.z);
    wt_s[(k+3)*NT + o] = f2bf(f.w);
  }
  __syncthreads();

  constexpr int OG = NT/4;
  const int og = tid % OG;
  const int rg = tid / OG;
  const int o  = og * 4;
  float acc[RPT][4];
  #pragma unroll
  for (int i=0;i<RPT;++i){ acc[i][0]=0.f; acc[i][1]=0.f; acc[i][2]=0.f; acc[i][3]=0.f; }

  for (int kp = 0; kp < K/2; ++kp) {
    const int k = kp*2;
    uint2 wv0 = *(const uint2*)&wt_s[(k+0)*NT + o];
    uint2 wv1 = *(const uint2*)&wt_s[(k+1)*NT + o];
    float w00 = bflo(wv0.x), w01 = bfhi(wv0.x), w02 = bflo(wv0.y), w03 = bfhi(wv0.y);
    float w10 = bflo(wv1.x), w11 = bfhi(wv1.x), w12 = bflo(wv1.y), w13 = bfhi(wv1.y);
    #pragma unroll
    for (int i=0;i<RPT;++i) {
      unsigned int av = *(const unsigned int*)&in_s[(rg*RPT+i)*KP + k];
      float a0 = bflo(av), a1 = bfhi(av);
      acc[i][0] += a0*w00 + a1*w10;
      acc[i][1] += a0*w01 + a1*w11;
      acc[i][2] += a0*w02 + a1*w12;
      acc[i][3] += a0*w03 + a1*w13;
    }
  }

  float4v bv = *(const float4v*)(bias + ob + o);
  float b2v[4] = {0.f,0.f,0.f,0.f};
  if (bias2 != nullptr) {
    float4v t2 = *(const float4v*)(bias2 + ob + o);
    b2v[0]=t2.x; b2v[1]=t2.y; b2v[2]=t2.z; b2v[3]=t2.w;
  }
  #pragma unroll
  for (int i=0;i<RPT;++i) {
    const int r = rg*RPT + i;
    float4v ov;
    #pragma unroll
    for (int j=0;j<4;++j) {
      float val = acc[i][j] + bv[j] + b2v[j];
      if (act == 2) {
        float m = bflo((unsigned int)in_s[r*KP + ob + o + j]);
        val = fsig(val) * m;
      }
      ov[j] = val;
    }
    if (act == 3) {
      #pragma unroll
      for (int j=0;j<4;++j) {
        int oo = ob + o + j;
        out[(size_t)(row0+r)*Ntotal + (oo & 127)*4 + (oo >> 7)] = ov[j];
      }
    } else {
      *(float4v*)(out + (size_t)(row0+r)*Ntotal + ob + o) = ov;
    }
  }
}

template<int K, int NT, int RPT>
__global__ __launch_bounds__(256) void rowgemm_kernel(
    const float* __restrict__ inA, const float* __restrict__ inB,
    const float* __restrict__ W, const float* __restrict__ bias,
    const float* __restrict__ bias2, float* __restrict__ out,
    int Ntotal, int act)
{
  __shared__ __align__(16) unsigned short in_s[32*(K+2)];
  __shared__ __align__(16) unsigned short wt_s[K*NT];
  rowgemm_body<K,NT,RPT>(in_s, wt_s, inA, inB, W, bias, bias2, out,
                         Ntotal, act, blockIdx.x*32, blockIdx.y*NT);
}

// Fused projections: blocks 0..95 -> x_proj, 96..191 -> y_proj (+Wvp_b)
__global__ __launch_bounds__(256) void proj_fused_kernel(
    const float* __restrict__ x, const float* __restrict__ y,
    const float* __restrict__ Wup_w, const float* __restrict__ Wup_b,
    const float* __restrict__ Wq_w, const float* __restrict__ Wq_b,
    const float* __restrict__ Wvp_b,
    float* __restrict__ xp, float* __restrict__ yp)
{
  __shared__ __align__(16) unsigned short in_s[32*130];
  __shared__ __align__(16) unsigned short wt_s[128*128];
  if (blockIdx.x < 96)
    rowgemm_body<128,128,4>(in_s, wt_s, x, nullptr, Wup_w, Wup_b, nullptr,
                            xp, 128, 0, blockIdx.x*32, 0);
  else
    rowgemm_body<128,128,4>(in_s, wt_s, y, nullptr, Wq_w, Wq_b, Wvp_b,
                            yp, 128, 0, (blockIdx.x-96)*32, 0);
}

// Fused additive attention (unchanged from round 5)
__global__ __launch_bounds__(256) void attn_kernel(
    const float* __restrict__ xp, const float* __restrict__ yp,
    const float* __restrict__ y, const unsigned char* __restrict__ xmask,
    const unsigned char* __restrict__ ymask, const float* __restrict__ Vw,
    const float* __restrict__ Vb, float* __restrict__ ct)
{
  __shared__ __align__(16) float xp_s[8][128];
  __shared__ __align__(16) float v2_s[128];
  __shared__ __align__(16) float yp_s[32][132];
  __shared__ __align__(16) float yc_s[32][132];
  __shared__ float xm_s[8];
  __shared__ float ym_s[32];
  __shared__ float sv_s;
  const int tid = threadIdx.x;
  const int b   = blockIdx.y;
  const int t0  = blockIdx.x * 8;
  const float C2 = 2.8853900817779268f;   // 2*log2(e)
  {
    int r = tid >> 5, k4 = (tid & 31) * 4;
    float4v f = *(const float4v*)(xp + ((size_t)(b*L_ + t0 + r))*H_ + k4);
    float4v g; g[0]=f[0]*C2; g[1]=f[1]*C2; g[2]=f[2]*C2; g[3]=f[3]*C2;
    *(float4v*)&xp_s[r][k4] = g;
    if (tid < 32) {
      float4v v = *(const float4v*)(Vw + tid*4);
      float4v v2; v2[0]=2.f*v[0]; v2[1]=2.f*v[1]; v2[2]=2.f*v[2]; v2[3]=2.f*v[3];
      *(float4v*)&v2_s[tid*4] = v2;
    }
    if (tid < 8) xm_s[tid] = xmask[b*L_ + t0 + tid] ? 0.f : 1.f;
  }
  __syncthreads();
  if (tid < 32) {
    float4v v = *(const float4v*)&v2_s[tid*4];
    float sm = (v[0]+v[1]) + (v[2]+v[3]);
    #pragma unroll
    for (int off = 16; off >= 1; off >>= 1) sm += __shfl_xor(sm, off);
    if (tid == 0) sv_s = 0.5f*sm + Vb[0];
  }

  float4v rp[4], ry[4];
  unsigned char ymb = 0;
  {
    #pragma unroll
    for (int it = 0; it < 4; ++it) {
      int idx = it*256 + tid; int r = idx >> 5; int k4 = (idx & 31) * 4;
      size_t base = ((size_t)(b*L_ + r))*H_ + k4;
      rp[it] = *(const float4v*)(yp + base);
      ry[it] = *(const float4v*)(y + base);
    }
    if (tid < 32) ymb = ymask[b*L_ + tid];
  }

  const int t = tid >> 5, u = tid & 31;
  float mrun = -__builtin_inff(), lrun = 0.f;
  float a0=0.f, a1=0.f, a2=0.f, a3=0.f;
  float svc = 0.f, xmv = 0.f;

  for (int c = 0; c < 12; ++c) {
    __syncthreads();
    #pragma unroll
    for (int it = 0; it < 4; ++it) {
      int idx = it*256 + tid; int r = idx >> 5; int k4 = (idx & 31) * 4;
      float4v sp; sp[0]=rp[it][0]*C2; sp[1]=rp[it][1]*C2; sp[2]=rp[it][2]*C2; sp[3]=rp[it][3]*C2;
      *(float4v*)&yp_s[r][k4] = sp;
      *(float4v*)&yc_s[r][k4] = ry[it];
    }
    if (tid < 32) ym_s[tid] = ymb ? 0.f : 1.f;
    __syncthreads();
    if (c == 0) { svc = sv_s; xmv = xm_s[t]; }
    if (c < 11) {
      #pragma unroll
      for (int it = 0; it < 4; ++it) {
        int idx = it*256 + tid; int r = idx >> 5; int k4 = (idx & 31) * 4;
        size_t base = ((size_t)(b*L_ + (c+1)*32 + r))*H_ + k4;
        rp[it] = *(const float4v*)(yp + base);
        ry[it] = *(const float4v*)(y + base);
      }
      if (tid < 32) ymb = ymask[b*L_ + (c+1)*32 + tid];
    }

    float sA = 0.f, sB = 0.f;
    {
      const float* yr = yp_s[u];
      const float* xr = xp_s[t];
      #pragma unroll 4
      for (int k = 0; k < 128; k += 4) {
        float4v yv = *(const float4v*)&yr[k];
        float4v xv = *(const float4v*)&xr[k];
        float4v vv = *(const float4v*)&v2_s[k];
        float e0 = __builtin_amdgcn_exp2f(xv[0] + yv[0]);
        sA -= vv[0] * __builtin_amdgcn_rcpf(e0 + 1.f);
        float e1 = __builtin_amdgcn_exp2f(xv[1] + yv[1]);
        sB -= vv[1] * __builtin_amdgcn_rcpf(e1 + 1.f);
        float e2 = __builtin_amdgcn_exp2f(xv[2] + yv[2]);
        sA -= vv[2] * __builtin_amdgcn_rcpf(e2 + 1.f);
        float e3 = __builtin_amdgcn_exp2f(xv[3] + yv[3]);
        sB -= vv[3] * __builtin_amdgcn_rcpf(e3 + 1.f);
      }
    }
    float ymv = ym_s[u];
    float s = (svc + sA + sB) * xmv * ymv;
    if (ymv == 0.f) s = -__builtin_inff();
    float mc = s;
    #pragma unroll
    for (int off = 16; off >= 1; off >>= 1) mc = fmaxf(mc, __shfl_xor(mc, off));
    float mnew = fmaxf(mrun, mc);
    float p  = __expf(s - mnew);
    float sc = __expf(mrun - mnew);
    float ps = p;
    #pragma unroll
    for (int off = 16; off >= 1; off >>= 1) ps += __shfl_xor(ps, off);
    lrun = lrun * sc + ps;
    mrun = mnew;
    a0 *= sc; a1 *= sc; a2 *= sc; a3 *= sc;
    #pragma unroll 8
    for (int j = 0; j < 32; ++j) {
      float pv = __shfl(p, j, 32);
      float4v yv = *(const float4v*)&yc_s[j][u*4];
      a0 += pv*yv[0]; a1 += pv*yv[1]; a2 += pv*yv[2]; a3 += pv*yv[3];
    }
  }
  float inv = __fdividef(1.f, lrun);
  float4v ov; ov[0]=a0*inv; ov[1]=a1*inv; ov[2]=a2*inv; ov[3]=a3*inv;
  *(float4v*)(ct + ((size_t)(b*L_ + t0 + t))*H_ + u*4) = ov;
}

// LSTM scan, round-6: 2-deep MFMA chains (8 independent), refill hoisted
// before MFMAs, gates computed on ALL lanes (C rows replicated since all A
// rows = h; only stores are quad0-masked), lgkm-only barrier.
__global__ __launch_bounds__(512) void lstm_kernel(
    const float* __restrict__ gx, const float* __restrict__ Whh,
    float* __restrict__ out)
{
  __shared__ __align__(16) unsigned short h_s[2][128];
  const int tid  = threadIdx.x;
  const int b    = blockIdx.x;
  const int w    = tid >> 6;
  const int l    = tid & 63;
  const int col  = l & 15;
  const int quad = l >> 4;

  short8 bf[4][4];
  #pragma unroll
  for (int nt = 0; nt < 4; ++nt) {
    const int n = nt*128 + w*16 + col;
    #pragma unroll
    for (int kt = 0; kt < 4; ++kt) {
      const int k0 = kt*32 + quad*8;
      const float* src = Whh + (size_t)n*H_ + k0;
      float4v f0 = *(const float4v*)(src);
      float4v f1 = *(const float4v*)(src + 4);
      short8 v;
      v[0]=(short)f2bf(f0[0]); v[1]=(short)f2bf(f0[1]); v[2]=(short)f2bf(f0[2]); v[3]=(short)f2bf(f0[3]);
      v[4]=(short)f2bf(f1[0]); v[5]=(short)f2bf(f1[1]); v[6]=(short)f2bf(f1[2]); v[7]=(short)f2bf(f1[3]);
      bf[nt][kt] = v;
    }
  }

  if (tid < 128) { h_s[0][tid] = 0; h_s[1][tid] = 0; }
  float cst = 0.f;
  const int goff = w*16 + col;
  const float* gbase = gx + (size_t)b*L_*512 + goff*4;
  float* outp = out + (size_t)b*L_*H_ + goff;
  float4v gbuf[4];
  #pragma unroll
  for (int s = 0; s < 4; ++s)
    gbuf[s] = *(const float4v*)(gbase + (size_t)s*512);
  const float4v z4 = {0.f,0.f,0.f,0.f};
  const float NL2E = -1.4426950408889634f;   // -log2(e)
  const float P2L2E = 2.8853900817779268f;   //  2*log2(e)
  __syncthreads();

  for (int t4 = 0; t4 < L_; t4 += 4) {
    #pragma unroll
    for (int s = 0; s < 4; ++s) {
      const int tstep = t4 + s;
      const unsigned short* hb = h_s[s & 1];
      short8 a0 = *(const short8*)&hb[ 0 + quad*8];
      short8 a1 = *(const short8*)&hb[32 + quad*8];
      short8 a2 = *(const short8*)&hb[64 + quad*8];
      short8 a3 = *(const short8*)&hb[96 + quad*8];
      float4v gcur = gbuf[s];
      if (tstep + 4 < L_)       // refill early: vmcnt latency overlaps MFMAs
        gbuf[s] = *(const float4v*)(gbase + (size_t)(tstep+4)*512);
      // 8 independent depth-2 MFMA chains
      float4v cA0 = __builtin_amdgcn_mfma_f32_16x16x32_bf16(a1, bf[0][1], z4, 0,0,0);
      float4v cB0 = __builtin_amdgcn_mfma_f32_16x16x32_bf16(a3, bf[0][3], z4, 0,0,0);
      float4v cA1 = __builtin_amdgcn_mfma_f32_16x16x32_bf16(a1, bf[1][1], z4, 0,0,0);
      float4v cB1 = __builtin_amdgcn_mfma_f32_16x16x32_bf16(a3, bf[1][3], z4, 0,0,0);
      float4v cA2 = __builtin_amdgcn_mfma_f32_16x16x32_bf16(a1, bf[2][1], z4, 0,0,0);
      float4v cB2 = __builtin_amdgcn_mfma_f32_16x16x32_bf16(a3, bf[2][3], z4, 0,0,0);
      float4v cA3 = __builtin_amdgcn_mfma_f32_16x16x32_bf16(a1, bf[3][1], z4, 0,0,0);
      float4v cB3 = __builtin_amdgcn_mfma_f32_16x16x32_bf16(a3, bf[3][3], z4, 0,0,0);
      cA0 = __builtin_amdgcn_mfma_f32_16x16x32_bf16(a0, bf[0][0], cA0, 0,0,0);
      cB0 = __builtin_amdgcn_mfma_f32_16x16x32_bf16(a2, bf[0][2], cB0, 0,0,0);
      cA1 = __builtin_amdgcn_mfma_f32_16x16x32_bf16(a0, bf[1][0], cA1, 0,0,0);
      cB1 = __builtin_amdgcn_mfma_f32_16x16x32_bf16(a2, bf[1][2], cB1, 0,0,0);
      cA2 = __builtin_amdgcn_mfma_f32_16x16x32_bf16(a0, bf[2][0], cA2, 0,0,0);
      cB2 = __builtin_amdgcn_mfma_f32_16x16x32_bf16(a2, bf[2][2], cB2, 0,0,0);
      cA3 = __builtin_amdgcn_mfma_f32_16x16x32_bf16(a0, bf[3][0], cA3, 0,0,0);
      cB3 = __builtin_amdgcn_mfma_f32_16x16x32_bf16(a2, bf[3][2], cB3, 0,0,0);
      float g0 = (cA0[0] + cB0[0]) + gcur[0];
      float g1 = (cA1[0] + cB1[0]) + gcur[1];
      float g2 = (cA2[0] + cB2[0]) + gcur[2];
      float g3 = (cA3[0] + cB3[0]) + gcur[3];
      // all lanes compute (values replicated across quads); stores masked
      float ig = __builtin_amdgcn_rcpf(1.f + __builtin_amdgcn_exp2f(NL2E*g0));
      float fg = __builtin_amdgcn_rcpf(1.f + __builtin_amdgcn_exp2f(NL2E*g1));
      float gg = 1.f - 2.f*__builtin_amdgcn_rcpf(__builtin_amdgcn_exp2f(P2L2E*g2) + 1.f);
      float og = __builtin_amdgcn_rcpf(1.f + __builtin_amdgcn_exp2f(NL2E*g3));
      cst = fg*cst + ig*gg;
      float hn = og * (1.f - 2.f*__builtin_amdgcn_rcpf(__builtin_amdgcn_exp2f(P2L2E*cst) + 1.f));
      if (quad == 0) {
        outp[(size_t)tstep*H_] = hn;
        h_s[(s+1)&1][goff] = f2bf(hn);
      }
      barrier_lds();
    }
  }
}

extern "C" void kernel_launch(void* const* d_in, const int* in_sizes, int n_in,
                              void* d_out, int out_size, void* d_ws, size_t ws_size,
                              hipStream_t stream)
{
  (void)in_sizes; (void)n_in; (void)out_size; (void)ws_size;
  const float* x     = (const float*)d_in[0];
  const unsigned char* xm = (const unsigned char*)d_in[1];
  const float* y     = (const float*)d_in[2];
  const unsigned char* ym = (const unsigned char*)d_in[3];
  const float* Wq_w  = (const float*)d_in[4];
  const float* Wq_b  = (const float*)d_in[5];
  const float* Wup_w = (const float*)d_in[6];
  const float* Wup_b = (const float*)d_in[7];
  const float* Wvp_b = (const float*)d_in[9];
  const float* V_w   = (const float*)d_in[10];
  const float* V_b   = (const float*)d_in[11];
  const float* Wg_w  = (const float*)d_in[12];
  const float* Wg_b  = (const float*)d_in[13];
  const float* W_ih  = (const float*)d_in[14];
  const float* W_hh  = (const float*)d_in[15];
  const float* b_ih  = (const float*)d_in[16];
  const float* b_hh  = (const float*)d_in[17];
  float* out = (float*)d_out;

  float* wsf   = (float*)d_ws;
  float* xp_ws = wsf;                  // [3072][128]
  float* yp_ws = xp_ws + 393216;       // [3072][128]
  float* ct_ws = yp_ws + 393216;       // [3072][128]
  float* li_ws = ct_ws + 393216;       // [3072][256]
  float* gx_ws = li_ws + 786432;       // [3072][512] gate-interleaved [t][h][4]

  proj_fused_kernel<<<dim3(192,1),256,0,stream>>>(x, y, Wup_w, Wup_b, Wq_w, Wq_b, Wvp_b, xp_ws, yp_ws);
  attn_kernel<<<dim3(48,8),256,0,stream>>>(xp_ws, yp_ws, y, xm, ym, V_w, V_b, ct_ws);
  rowgemm_kernel<256,64,2><<<dim3(96,4),256,0,stream>>>(x, ct_ws, Wg_w, Wg_b, nullptr, li_ws, 256, 2);
  rowgemm_kernel<256,64,2><<<dim3(96,8),256,0,stream>>>(li_ws, nullptr, W_ih, b_ih, b_hh, gx_ws, 512, 3);
  lstm_kernel<<<dim3(8),512,0,stream>>>(gx_ws, W_hh, out);
}

// Round 7
// 364.030 us; speedup vs baseline: 1.6134x; 1.1350x over previous
//
#include <hip/hip_runtime.h>
#include <hip/hip_bf16.h>
#include <math.h>

typedef __attribute__((ext_vector_type(4))) float  float4v;
typedef __attribute__((ext_vector_type(2))) float  float2v;
typedef __attribute__((ext_vector_type(8))) short  short8;

#define B_ 8
#define L_ 384
#define H_ 128

__device__ __forceinline__ float bflo(unsigned int u){ unsigned int t = u << 16; float f; __builtin_memcpy(&f,&t,4); return f; }
__device__ __forceinline__ unsigned short f2bf(float f){
  unsigned int t; __builtin_memcpy(&t,&f,4);
  return (unsigned short)((t + 0x7fffu + ((t>>16)&1u)) >> 16);
}
__device__ __forceinline__ float fsig(float x){ return __fdividef(1.f, 1.f + __expf(-x)); }

// lgkm-only barrier: LDS ordering without draining in-flight global loads/stores
__device__ __forceinline__ void barrier_lds(){
  asm volatile("s_waitcnt lgkmcnt(0)\n\ts_barrier" ::: "memory");
}

// ---------------- MFMA row-GEMM ----------------
// out[row][n] = act( in[row] . W[n][:] + bias[n] (+bias2[n]) )
// Block: 256 thr = 4 waves; tile M=32 rows x N=64 outs (wave w: n-slice w*16).
// Weights live in registers as verified 16x16x32 B-fragments; input staged
// once in LDS as bf16 (KP=K+2 pad -> +1-bank row stride). Single barrier.
// act==2: out = sigmoid(v) * merge[row][n]  (merge = staged input, Ntotal==K)
// act==3: gate-interleaved scatter out[row*512 + (n&127)*4 + (n>>7)]
template<int K>
__device__ __forceinline__ void mfma_rowgemm_body(
    unsigned short* in_s,
    const float* __restrict__ inA, const float* __restrict__ inB,
    const float* __restrict__ W, const float* __restrict__ bias,
    const float* __restrict__ bias2, float* __restrict__ out,
    int Ntotal, int act, int row0, int ob)
{
  constexpr int KP = K + 2;
  const int tid  = threadIdx.x;
  const int w    = tid >> 6;
  const int l    = tid & 63;
  const int c    = l & 15;
  const int quad = l >> 4;

  // stage 32 rows x K input as bf16
  #pragma unroll
  for (int it = 0; it < K/32; ++it) {
    int idx = it*256 + tid;
    int r = idx / (K/4);
    int k = (idx % (K/4)) * 4;
    float4v f;
    if (inB != nullptr && k >= 128)
      f = *(const float4v*)(inB + (size_t)(row0+r)*128 + (k-128));
    else if (inB != nullptr)
      f = *(const float4v*)(inA + (size_t)(row0+r)*128 + k);
    else
      f = *(const float4v*)(inA + (size_t)(row0+r)*K + k);
    unsigned int p0 = (unsigned int)f2bf(f.x) | ((unsigned int)f2bf(f.y) << 16);
    unsigned int p1 = (unsigned int)f2bf(f.z) | ((unsigned int)f2bf(f.w) << 16);
    *(unsigned int*)&in_s[r*KP + k]     = p0;
    *(unsigned int*)&in_s[r*KP + k + 2] = p1;
  }

  // B-fragments from global (L2-resident weights): lane holds
  // B[k=kt*32+quad*8+j][n=ob+w*16+c] = W[n][k]   (layout verified via lstm)
  const int n = ob + w*16 + c;
  short8 bfr[K/32];
  #pragma unroll
  for (int kt = 0; kt < K/32; ++kt) {
    const float* src = W + (size_t)n*K + kt*32 + quad*8;
    float4v f0 = *(const float4v*)(src);
    float4v f1 = *(const float4v*)(src + 4);
    short8 v;
    v[0]=(short)f2bf(f0[0]); v[1]=(short)f2bf(f0[1]); v[2]=(short)f2bf(f0[2]); v[3]=(short)f2bf(f0[3]);
    v[4]=(short)f2bf(f1[0]); v[5]=(short)f2bf(f1[1]); v[6]=(short)f2bf(f1[2]); v[7]=(short)f2bf(f1[3]);
    bfr[kt] = v;
  }
  __syncthreads();

  const float4v z4 = {0.f,0.f,0.f,0.f};
  float4v acc0 = z4, acc1 = z4;   // m-tiles 0 (rows 0-15) and 1 (rows 16-31)
  #pragma unroll
  for (int kt = 0; kt < K/32; ++kt) {
    short8 a0 = *(const short8*)&in_s[(c     )*KP + kt*32 + quad*8];
    short8 a1 = *(const short8*)&in_s[(16 + c)*KP + kt*32 + quad*8];
    acc0 = __builtin_amdgcn_mfma_f32_16x16x32_bf16(a0, bfr[kt], acc0, 0,0,0);
    acc1 = __builtin_amdgcn_mfma_f32_16x16x32_bf16(a1, bfr[kt], acc1, 0,0,0);
  }

  // epilogue: lane holds D[m=mt*16+quad*4+r][n]
  float bv = bias[n] + (bias2 ? bias2[n] : 0.f);
  #pragma unroll
  for (int mt = 0; mt < 2; ++mt) {
    float4v A = mt ? acc1 : acc0;
    #pragma unroll
    for (int r = 0; r < 4; ++r) {
      int m = mt*16 + quad*4 + r;
      float val = A[r] + bv;
      if (act == 2) {
        float mg = bflo((unsigned int)in_s[m*KP + n]);
        val = fsig(val) * mg;
      }
      if (act == 3)
        out[(size_t)(row0+m)*Ntotal + (n & 127)*4 + (n >> 7)] = val;
      else
        out[(size_t)(row0+m)*Ntotal + n] = val;
    }
  }
}

template<int K>
__global__ __launch_bounds__(256) void mfma_rowgemm_kernel(
    const float* __restrict__ inA, const float* __restrict__ inB,
    const float* __restrict__ W, const float* __restrict__ bias,
    const float* __restrict__ bias2, float* __restrict__ out,
    int Ntotal, int act)
{
  __shared__ __align__(16) unsigned short in_s[32*(K+2)];
  mfma_rowgemm_body<K>(in_s, inA, inB, W, bias, bias2, out,
                       Ntotal, act, blockIdx.x*32, blockIdx.y*64);
}

// Fused projections: blocks 0..191 -> x_proj, 192..383 -> y_proj (+Wvp_b)
__global__ __launch_bounds__(256) void proj_mfma_kernel(
    const float* __restrict__ x, const float* __restrict__ y,
    const float* __restrict__ Wup_w, const float* __restrict__ Wup_b,
    const float* __restrict__ Wq_w, const float* __restrict__ Wq_b,
    const float* __restrict__ Wvp_b,
    float* __restrict__ xp, float* __restrict__ yp)
{
  __shared__ __align__(16) unsigned short in_s[32*130];
  int bx = blockIdx.x;
  if (bx < 192)
    mfma_rowgemm_body<128>(in_s, x, nullptr, Wup_w, Wup_b, nullptr,
                           xp, 128, 0, (bx>>1)*32, (bx&1)*64);
  else {
    bx -= 192;
    mfma_rowgemm_body<128>(in_s, y, nullptr, Wq_w, Wq_b, Wvp_b,
                           yp, 128, 0, (bx>>1)*32, (bx&1)*64);
  }
}

// Fused additive attention (unchanged from round 6)
__global__ __launch_bounds__(256) void attn_kernel(
    const float* __restrict__ xp, const float* __restrict__ yp,
    const float* __restrict__ y, const unsigned char* __restrict__ xmask,
    const unsigned char* __restrict__ ymask, const float* __restrict__ Vw,
    const float* __restrict__ Vb, float* __restrict__ ct)
{
  __shared__ __align__(16) float xp_s[8][128];
  __shared__ __align__(16) float v2_s[128];
  __shared__ __align__(16) float yp_s[32][132];
  __shared__ __align__(16) float yc_s[32][132];
  __shared__ float xm_s[8];
  __shared__ float ym_s[32];
  __shared__ float sv_s;
  const int tid = threadIdx.x;
  const int b   = blockIdx.y;
  const int t0  = blockIdx.x * 8;
  const float C2 = 2.8853900817779268f;   // 2*log2(e)
  {
    int r = tid >> 5, k4 = (tid & 31) * 4;
    float4v f = *(const float4v*)(xp + ((size_t)(b*L_ + t0 + r))*H_ + k4);
    float4v g; g[0]=f[0]*C2; g[1]=f[1]*C2; g[2]=f[2]*C2; g[3]=f[3]*C2;
    *(float4v*)&xp_s[r][k4] = g;
    if (tid < 32) {
      float4v v = *(const float4v*)(Vw + tid*4);
      float4v v2; v2[0]=2.f*v[0]; v2[1]=2.f*v[1]; v2[2]=2.f*v[2]; v2[3]=2.f*v[3];
      *(float4v*)&v2_s[tid*4] = v2;
    }
    if (tid < 8) xm_s[tid] = xmask[b*L_ + t0 + tid] ? 0.f : 1.f;
  }
  __syncthreads();
  if (tid < 32) {
    float4v v = *(const float4v*)&v2_s[tid*4];
    float sm = (v[0]+v[1]) + (v[2]+v[3]);
    #pragma unroll
    for (int off = 16; off >= 1; off >>= 1) sm += __shfl_xor(sm, off);
    if (tid == 0) sv_s = 0.5f*sm + Vb[0];
  }

  float4v rp[4], ry[4];
  unsigned char ymb = 0;
  {
    #pragma unroll
    for (int it = 0; it < 4; ++it) {
      int idx = it*256 + tid; int r = idx >> 5; int k4 = (idx & 31) * 4;
      size_t base = ((size_t)(b*L_ + r))*H_ + k4;
      rp[it] = *(const float4v*)(yp + base);
      ry[it] = *(const float4v*)(y + base);
    }
    if (tid < 32) ymb = ymask[b*L_ + tid];
  }

  const int t = tid >> 5, u = tid & 31;
  float mrun = -__builtin_inff(), lrun = 0.f;
  float a0=0.f, a1=0.f, a2=0.f, a3=0.f;
  float svc = 0.f, xmv = 0.f;

  for (int c = 0; c < 12; ++c) {
    __syncthreads();
    #pragma unroll
    for (int it = 0; it < 4; ++it) {
      int idx = it*256 + tid; int r = idx >> 5; int k4 = (idx & 31) * 4;
      float4v sp; sp[0]=rp[it][0]*C2; sp[1]=rp[it][1]*C2; sp[2]=rp[it][2]*C2; sp[3]=rp[it][3]*C2;
      *(float4v*)&yp_s[r][k4] = sp;
      *(float4v*)&yc_s[r][k4] = ry[it];
    }
    if (tid < 32) ym_s[tid] = ymb ? 0.f : 1.f;
    __syncthreads();
    if (c == 0) { svc = sv_s; xmv = xm_s[t]; }
    if (c < 11) {
      #pragma unroll
      for (int it = 0; it < 4; ++it) {
        int idx = it*256 + tid; int r = idx >> 5; int k4 = (idx & 31) * 4;
        size_t base = ((size_t)(b*L_ + (c+1)*32 + r))*H_ + k4;
        rp[it] = *(const float4v*)(yp + base);
        ry[it] = *(const float4v*)(y + base);
      }
      if (tid < 32) ymb = ymask[b*L_ + (c+1)*32 + tid];
    }

    float sA = 0.f, sB = 0.f;
    {
      const float* yr = yp_s[u];
      const float* xr = xp_s[t];
      #pragma unroll 4
      for (int k = 0; k < 128; k += 4) {
        float4v yv = *(const float4v*)&yr[k];
        float4v xv = *(const float4v*)&xr[k];
        float4v vv = *(const float4v*)&v2_s[k];
        float e0 = __builtin_amdgcn_exp2f(xv[0] + yv[0]);
        sA -= vv[0] * __builtin_amdgcn_rcpf(e0 + 1.f);
        float e1 = __builtin_amdgcn_exp2f(xv[1] + yv[1]);
        sB -= vv[1] * __builtin_amdgcn_rcpf(e1 + 1.f);
        float e2 = __builtin_amdgcn_exp2f(xv[2] + yv[2]);
        sA -= vv[2] * __builtin_amdgcn_rcpf(e2 + 1.f);
        float e3 = __builtin_amdgcn_exp2f(xv[3] + yv[3]);
        sB -= vv[3] * __builtin_amdgcn_rcpf(e3 + 1.f);
      }
    }
    float ymv = ym_s[u];
    float s = (svc + sA + sB) * xmv * ymv;
    if (ymv == 0.f) s = -__builtin_inff();
    float mc = s;
    #pragma unroll
    for (int off = 16; off >= 1; off >>= 1) mc = fmaxf(mc, __shfl_xor(mc, off));
    float mnew = fmaxf(mrun, mc);
    float p  = __expf(s - mnew);
    float sc = __expf(mrun - mnew);
    float ps = p;
    #pragma unroll
    for (int off = 16; off >= 1; off >>= 1) ps += __shfl_xor(ps, off);
    lrun = lrun * sc + ps;
    mrun = mnew;
    a0 *= sc; a1 *= sc; a2 *= sc; a3 *= sc;
    #pragma unroll 8
    for (int j = 0; j < 32; ++j) {
      float pv = __shfl(p, j, 32);
      float4v yv = *(const float4v*)&yc_s[j][u*4];
      a0 += pv*yv[0]; a1 += pv*yv[1]; a2 += pv*yv[2]; a3 += pv*yv[3];
    }
  }
  float inv = __fdividef(1.f, lrun);
  float4v ov; ov[0]=a0*inv; ov[1]=a1*inv; ov[2]=a2*inv; ov[3]=a3*inv;
  *(float4v*)(ct + ((size_t)(b*L_ + t0 + t))*H_ + u*4) = ov;
}

// LSTM scan — round-5 body (measured 180 µs; round-6 variant regressed).
__global__ __launch_bounds__(512) void lstm_kernel(
    const float* __restrict__ gx, const float* __restrict__ Whh,
    float* __restrict__ out)
{
  __shared__ __align__(16) unsigned short h_s[2][128];
  const int tid  = threadIdx.x;
  const int b    = blockIdx.x;
  const int w    = tid >> 6;
  const int l    = tid & 63;
  const int col  = l & 15;
  const int quad = l >> 4;

  short8 bf[4][4];
  #pragma unroll
  for (int nt = 0; nt < 4; ++nt) {
    const int n = nt*128 + w*16 + col;
    #pragma unroll
    for (int kt = 0; kt < 4; ++kt) {
      const int k0 = kt*32 + quad*8;
      const float* src = Whh + (size_t)n*H_ + k0;
      float4v f0 = *(const float4v*)(src);
      float4v f1 = *(const float4v*)(src + 4);
      short8 v;
      v[0]=(short)f2bf(f0[0]); v[1]=(short)f2bf(f0[1]); v[2]=(short)f2bf(f0[2]); v[3]=(short)f2bf(f0[3]);
      v[4]=(short)f2bf(f1[0]); v[5]=(short)f2bf(f1[1]); v[6]=(short)f2bf(f1[2]); v[7]=(short)f2bf(f1[3]);
      bf[nt][kt] = v;
    }
  }

  if (tid < 128) { h_s[0][tid] = 0; h_s[1][tid] = 0; }
  float cst = 0.f;
  const int goff = w*16 + col;
  const float* gbase = gx + (size_t)b*L_*512 + goff*4;
  float* outp = out + (size_t)b*L_*H_ + goff;
  float4v gbuf[4];
  #pragma unroll
  for (int s = 0; s < 4; ++s)
    gbuf[s] = *(const float4v*)(gbase + (size_t)s*512);
  const float4v z4 = {0.f,0.f,0.f,0.f};
  const float NL2E = -1.4426950408889634f;   // -log2(e)
  const float P2L2E = 2.8853900817779268f;   //  2*log2(e)
  __syncthreads();

  for (int t4 = 0; t4 < L_; t4 += 4) {
    #pragma unroll
    for (int s = 0; s < 4; ++s) {
      const int tstep = t4 + s;
      const unsigned short* hb = h_s[s & 1];
      short8 a[4];
      #pragma unroll
      for (int kt=0;kt<4;++kt) a[kt] = *(const short8*)&hb[kt*32 + quad*8];
      float4v c0 = z4, c1 = z4, c2 = z4, c3 = z4;
      #pragma unroll
      for (int kt=0;kt<4;++kt) {
        c0 = __builtin_amdgcn_mfma_f32_16x16x32_bf16(a[kt], bf[0][kt], c0, 0,0,0);
        c1 = __builtin_amdgcn_mfma_f32_16x16x32_bf16(a[kt], bf[1][kt], c1, 0,0,0);
        c2 = __builtin_amdgcn_mfma_f32_16x16x32_bf16(a[kt], bf[2][kt], c2, 0,0,0);
        c3 = __builtin_amdgcn_mfma_f32_16x16x32_bf16(a[kt], bf[3][kt], c3, 0,0,0);
      }
      float g0 = c0[0] + gbuf[s][0];
      float g1 = c1[0] + gbuf[s][1];
      float g2 = c2[0] + gbuf[s][2];
      float g3 = c3[0] + gbuf[s][3];
      if (tstep + 4 < L_)
        gbuf[s] = *(const float4v*)(gbase + (size_t)(tstep+4)*512);
      if (quad == 0) {
        float ig = __builtin_amdgcn_rcpf(1.f + __builtin_amdgcn_exp2f(NL2E*g0));
        float fg = __builtin_amdgcn_rcpf(1.f + __builtin_amdgcn_exp2f(NL2E*g1));
        float gg = 1.f - 2.f*__builtin_amdgcn_rcpf(__builtin_amdgcn_exp2f(P2L2E*g2) + 1.f);
        float og = __builtin_amdgcn_rcpf(1.f + __builtin_amdgcn_exp2f(NL2E*g3));
        cst = fg*cst + ig*gg;
        float hn = og * (1.f - 2.f*__builtin_amdgcn_rcpf(__builtin_amdgcn_exp2f(P2L2E*cst) + 1.f));
        outp[(size_t)tstep*H_] = hn;
        h_s[(s+1)&1][goff] = f2bf(hn);
      }
      barrier_lds();
    }
  }
}

extern "C" void kernel_launch(void* const* d_in, const int* in_sizes, int n_in,
                              void* d_out, int out_size, void* d_ws, size_t ws_size,
                              hipStream_t stream)
{
  (void)in_sizes; (void)n_in; (void)out_size; (void)ws_size;
  const float* x     = (const float*)d_in[0];
  const unsigned char* xm = (const unsigned char*)d_in[1];
  const float* y     = (const float*)d_in[2];
  const unsigned char* ym = (const unsigned char*)d_in[3];
  const float* Wq_w  = (const float*)d_in[4];
  const float* Wq_b  = (const float*)d_in[5];
  const float* Wup_w = (const float*)d_in[6];
  const float* Wup_b = (const float*)d_in[7];
  const float* Wvp_b = (const float*)d_in[9];
  const float* V_w   = (const float*)d_in[10];
  const float* V_b   = (const float*)d_in[11];
  const float* Wg_w  = (const float*)d_in[12];
  const float* Wg_b  = (const float*)d_in[13];
  const float* W_ih  = (const float*)d_in[14];
  const float* W_hh  = (const float*)d_in[15];
  const float* b_ih  = (const float*)d_in[16];
  const float* b_hh  = (const float*)d_in[17];
  float* out = (float*)d_out;

  float* wsf   = (float*)d_ws;
  float* xp_ws = wsf;                  // [3072][128]
  float* yp_ws = xp_ws + 393216;       // [3072][128]
  float* ct_ws = yp_ws + 393216;       // [3072][128]
  float* li_ws = ct_ws + 393216;       // [3072][256]
  float* gx_ws = li_ws + 786432;       // [3072][512] gate-interleaved [t][h][4]

  proj_mfma_kernel<<<dim3(384),256,0,stream>>>(x, y, Wup_w, Wup_b, Wq_w, Wq_b, Wvp_b, xp_ws, yp_ws);
  attn_kernel<<<dim3(48,8),256,0,stream>>>(xp_ws, yp_ws, y, xm, ym, V_w, V_b, ct_ws);
  mfma_rowgemm_kernel<256><<<dim3(96,4),256,0,stream>>>(x, ct_ws, Wg_w, Wg_b, nullptr, li_ws, 256, 2);
  mfma_rowgemm_kernel<256><<<dim3(96,8),256,0,stream>>>(li_ws, nullptr, W_ih, b_ih, b_hh, gx_ws, 512, 3);
  lstm_kernel<<<dim3(8),512,0,stream>>>(gx_ws, W_hh, out);
}

// Round 8
// 345.405 us; speedup vs baseline: 1.7004x; 1.0539x over previous
//
#include <hip/hip_runtime.h>
#include <hip/hip_bf16.h>
#include <math.h>

typedef __attribute__((ext_vector_type(4))) float  float4v;
typedef __attribute__((ext_vector_type(2))) float  float2v;
typedef __attribute__((ext_vector_type(8))) short  short8;

#define B_ 8
#define L_ 384
#define H_ 128

__device__ __forceinline__ float bflo(unsigned int u){ unsigned int t = u << 16; float f; __builtin_memcpy(&f,&t,4); return f; }
__device__ __forceinline__ unsigned short f2bf(float f){
  unsigned int t; __builtin_memcpy(&t,&f,4);
  return (unsigned short)((t + 0x7fffu + ((t>>16)&1u)) >> 16);
}
__device__ __forceinline__ float fsig(float x){ return __fdividef(1.f, 1.f + __expf(-x)); }

// lgkm-only barrier: LDS ordering without draining in-flight global loads/stores
__device__ __forceinline__ void barrier_lds(){
  asm volatile("s_waitcnt lgkmcnt(0)\n\ts_barrier" ::: "memory");
}

// ---------------- MFMA row-GEMM (unchanged from round 7) ----------------
template<int K>
__device__ __forceinline__ void mfma_rowgemm_body(
    unsigned short* in_s,
    const float* __restrict__ inA, const float* __restrict__ inB,
    const float* __restrict__ W, const float* __restrict__ bias,
    const float* __restrict__ bias2, float* __restrict__ out,
    int Ntotal, int act, int row0, int ob)
{
  constexpr int KP = K + 2;
  const int tid  = threadIdx.x;
  const int w    = tid >> 6;
  const int l    = tid & 63;
  const int c    = l & 15;
  const int quad = l >> 4;

  #pragma unroll
  for (int it = 0; it < K/32; ++it) {
    int idx = it*256 + tid;
    int r = idx / (K/4);
    int k = (idx % (K/4)) * 4;
    float4v f;
    if (inB != nullptr && k >= 128)
      f = *(const float4v*)(inB + (size_t)(row0+r)*128 + (k-128));
    else if (inB != nullptr)
      f = *(const float4v*)(inA + (size_t)(row0+r)*128 + k);
    else
      f = *(const float4v*)(inA + (size_t)(row0+r)*K + k);
    unsigned int p0 = (unsigned int)f2bf(f.x) | ((unsigned int)f2bf(f.y) << 16);
    unsigned int p1 = (unsigned int)f2bf(f.z) | ((unsigned int)f2bf(f.w) << 16);
    *(unsigned int*)&in_s[r*KP + k]     = p0;
    *(unsigned int*)&in_s[r*KP + k + 2] = p1;
  }

  const int n = ob + w*16 + c;
  short8 bfr[K/32];
  #pragma unroll
  for (int kt = 0; kt < K/32; ++kt) {
    const float* src = W + (size_t)n*K + kt*32 + quad*8;
    float4v f0 = *(const float4v*)(src);
    float4v f1 = *(const float4v*)(src + 4);
    short8 v;
    v[0]=(short)f2bf(f0[0]); v[1]=(short)f2bf(f0[1]); v[2]=(short)f2bf(f0[2]); v[3]=(short)f2bf(f0[3]);
    v[4]=(short)f2bf(f1[0]); v[5]=(short)f2bf(f1[1]); v[6]=(short)f2bf(f1[2]); v[7]=(short)f2bf(f1[3]);
    bfr[kt] = v;
  }
  __syncthreads();

  const float4v z4 = {0.f,0.f,0.f,0.f};
  float4v acc0 = z4, acc1 = z4;
  #pragma unroll
  for (int kt = 0; kt < K/32; ++kt) {
    short8 a0 = *(const short8*)&in_s[(c     )*KP + kt*32 + quad*8];
    short8 a1 = *(const short8*)&in_s[(16 + c)*KP + kt*32 + quad*8];
    acc0 = __builtin_amdgcn_mfma_f32_16x16x32_bf16(a0, bfr[kt], acc0, 0,0,0);
    acc1 = __builtin_amdgcn_mfma_f32_16x16x32_bf16(a1, bfr[kt], acc1, 0,0,0);
  }

  float bv = bias[n] + (bias2 ? bias2[n] : 0.f);
  #pragma unroll
  for (int mt = 0; mt < 2; ++mt) {
    float4v A = mt ? acc1 : acc0;
    #pragma unroll
    for (int r = 0; r < 4; ++r) {
      int m = mt*16 + quad*4 + r;
      float val = A[r] + bv;
      if (act == 2) {
        float mg = bflo((unsigned int)in_s[m*KP + n]);
        val = fsig(val) * mg;
      }
      if (act == 3)
        out[(size_t)(row0+m)*Ntotal + (n & 127)*4 + (n >> 7)] = val;
      else
        out[(size_t)(row0+m)*Ntotal + n] = val;
    }
  }
}

template<int K>
__global__ __launch_bounds__(256) void mfma_rowgemm_kernel(
    const float* __restrict__ inA, const float* __restrict__ inB,
    const float* __restrict__ W, const float* __restrict__ bias,
    const float* __restrict__ bias2, float* __restrict__ out,
    int Ntotal, int act)
{
  __shared__ __align__(16) unsigned short in_s[32*(K+2)];
  mfma_rowgemm_body<K>(in_s, inA, inB, W, bias, bias2, out,
                       Ntotal, act, blockIdx.x*32, blockIdx.y*64);
}

__global__ __launch_bounds__(256) void proj_mfma_kernel(
    const float* __restrict__ x, const float* __restrict__ y,
    const float* __restrict__ Wup_w, const float* __restrict__ Wup_b,
    const float* __restrict__ Wq_w, const float* __restrict__ Wq_b,
    const float* __restrict__ Wvp_b,
    float* __restrict__ xp, float* __restrict__ yp)
{
  __shared__ __align__(16) unsigned short in_s[32*130];
  int bx = blockIdx.x;
  if (bx < 192)
    mfma_rowgemm_body<128>(in_s, x, nullptr, Wup_w, Wup_b, nullptr,
                           xp, 128, 0, (bx>>1)*32, (bx&1)*64);
  else {
    bx -= 192;
    mfma_rowgemm_body<128>(in_s, y, nullptr, Wq_w, Wq_b, Wvp_b,
                           yp, 128, 0, (bx>>1)*32, (bx&1)*64);
  }
}

// Fused additive attention, round-8: j-dimension split in 2 halves
// (blockIdx.z) for 2x occupancy; emits per-half online-softmax partials
// (unnormalized ct, m, l) merged by attn_merge_kernel.
__global__ __launch_bounds__(256) void attn_kernel(
    const float* __restrict__ xp, const float* __restrict__ yp,
    const float* __restrict__ y, const unsigned char* __restrict__ xmask,
    const unsigned char* __restrict__ ymask, const float* __restrict__ Vw,
    const float* __restrict__ Vb,
    float* __restrict__ ctp0, float* __restrict__ ctp1,
    float* __restrict__ ml)
{
  __shared__ __align__(16) float xp_s[8][128];
  __shared__ __align__(16) float v2_s[128];
  __shared__ __align__(16) float yp_s[32][132];
  __shared__ __align__(16) float yc_s[32][132];
  __shared__ float xm_s[8];
  __shared__ float ym_s[32];
  __shared__ float sv_s;
  const int tid = threadIdx.x;
  const int b   = blockIdx.y;
  const int t0  = blockIdx.x * 8;
  const int jh  = blockIdx.z;      // 0: chunks 0..5, 1: chunks 6..11
  const float C2 = 2.8853900817779268f;   // 2*log2(e)
  {
    int r = tid >> 5, k4 = (tid & 31) * 4;
    float4v f = *(const float4v*)(xp + ((size_t)(b*L_ + t0 + r))*H_ + k4);
    float4v g; g[0]=f[0]*C2; g[1]=f[1]*C2; g[2]=f[2]*C2; g[3]=f[3]*C2;
    *(float4v*)&xp_s[r][k4] = g;
    if (tid < 32) {
      float4v v = *(const float4v*)(Vw + tid*4);
      float4v v2; v2[0]=2.f*v[0]; v2[1]=2.f*v[1]; v2[2]=2.f*v[2]; v2[3]=2.f*v[3];
      *(float4v*)&v2_s[tid*4] = v2;
    }
    if (tid < 8) xm_s[tid] = xmask[b*L_ + t0 + tid] ? 0.f : 1.f;
  }
  __syncthreads();
  if (tid < 32) {
    float4v v = *(const float4v*)&v2_s[tid*4];
    float sm = (v[0]+v[1]) + (v[2]+v[3]);
    #pragma unroll
    for (int off = 16; off >= 1; off >>= 1) sm += __shfl_xor(sm, off);
    if (tid == 0) sv_s = 0.5f*sm + Vb[0];
  }

  float4v rp[4], ry[4];
  unsigned char ymb = 0;
  {
    #pragma unroll
    for (int it = 0; it < 4; ++it) {
      int idx = it*256 + tid; int r = idx >> 5; int k4 = (idx & 31) * 4;
      size_t base = ((size_t)(b*L_ + jh*192 + r))*H_ + k4;
      rp[it] = *(const float4v*)(yp + base);
      ry[it] = *(const float4v*)(y + base);
    }
    if (tid < 32) ymb = ymask[b*L_ + jh*192 + tid];
  }

  const int t = tid >> 5, u = tid & 31;
  float mrun = -__builtin_inff(), lrun = 0.f;
  float a0=0.f, a1=0.f, a2=0.f, a3=0.f;
  float svc = 0.f, xmv = 0.f;

  for (int c = 0; c < 6; ++c) {
    __syncthreads();
    #pragma unroll
    for (int it = 0; it < 4; ++it) {
      int idx = it*256 + tid; int r = idx >> 5; int k4 = (idx & 31) * 4;
      float4v sp; sp[0]=rp[it][0]*C2; sp[1]=rp[it][1]*C2; sp[2]=rp[it][2]*C2; sp[3]=rp[it][3]*C2;
      *(float4v*)&yp_s[r][k4] = sp;
      *(float4v*)&yc_s[r][k4] = ry[it];
    }
    if (tid < 32) ym_s[tid] = ymb ? 0.f : 1.f;
    __syncthreads();
    if (c == 0) { svc = sv_s; xmv = xm_s[t]; }
    if (c < 5) {
      #pragma unroll
      for (int it = 0; it < 4; ++it) {
        int idx = it*256 + tid; int r = idx >> 5; int k4 = (idx & 31) * 4;
        size_t base = ((size_t)(b*L_ + jh*192 + (c+1)*32 + r))*H_ + k4;
        rp[it] = *(const float4v*)(yp + base);
        ry[it] = *(const float4v*)(y + base);
      }
      if (tid < 32) ymb = ymask[b*L_ + jh*192 + (c+1)*32 + tid];
    }

    float sA = 0.f, sB = 0.f;
    {
      const float* yr = yp_s[u];
      const float* xr = xp_s[t];
      #pragma unroll 4
      for (int k = 0; k < 128; k += 4) {
        float4v yv = *(const float4v*)&yr[k];
        float4v xv = *(const float4v*)&xr[k];
        float4v vv = *(const float4v*)&v2_s[k];
        float e0 = __builtin_amdgcn_exp2f(xv[0] + yv[0]);
        sA -= vv[0] * __builtin_amdgcn_rcpf(e0 + 1.f);
        float e1 = __builtin_amdgcn_exp2f(xv[1] + yv[1]);
        sB -= vv[1] * __builtin_amdgcn_rcpf(e1 + 1.f);
        float e2 = __builtin_amdgcn_exp2f(xv[2] + yv[2]);
        sA -= vv[2] * __builtin_amdgcn_rcpf(e2 + 1.f);
        float e3 = __builtin_amdgcn_exp2f(xv[3] + yv[3]);
        sB -= vv[3] * __builtin_amdgcn_rcpf(e3 + 1.f);
      }
    }
    float ymv = ym_s[u];
    float s = (svc + sA + sB) * xmv * ymv;
    if (ymv == 0.f) s = -__builtin_inff();
    float mc = s;
    #pragma unroll
    for (int off = 16; off >= 1; off >>= 1) mc = fmaxf(mc, __shfl_xor(mc, off));
    float mnew = fmaxf(mrun, mc);
    float p  = __expf(s - mnew);
    float sc = __expf(mrun - mnew);
    float ps = p;
    #pragma unroll
    for (int off = 16; off >= 1; off >>= 1) ps += __shfl_xor(ps, off);
    lrun = lrun * sc + ps;
    mrun = mnew;
    a0 *= sc; a1 *= sc; a2 *= sc; a3 *= sc;
    #pragma unroll 8
    for (int j = 0; j < 32; ++j) {
      float pv = __shfl(p, j, 32);
      float4v yv = *(const float4v*)&yc_s[j][u*4];
      a0 += pv*yv[0]; a1 += pv*yv[1]; a2 += pv*yv[2]; a3 += pv*yv[3];
    }
  }
  const int row = b*L_ + t0 + t;
  float* ctp = jh ? ctp1 : ctp0;
  float4v ov; ov[0]=a0; ov[1]=a1; ov[2]=a2; ov[3]=a3;     // unnormalized
  *(float4v*)(ctp + (size_t)row*H_ + u*4) = ov;
  if (u == 0) {
    ml[(jh*2+0)*3072 + row] = mrun;
    ml[(jh*2+1)*3072 + row] = lrun;
  }
}

// Merge the two j-half partials: ct = (ct0*e0 + ct1*e1) / (l0*e0 + l1*e1)
__global__ __launch_bounds__(256) void attn_merge_kernel(
    const float* __restrict__ ctp0, const float* __restrict__ ctp1,
    const float* __restrict__ ml, float* __restrict__ ct)
{
  const int tid = threadIdx.x;
  const int row = blockIdx.x*8 + (tid >> 5);
  const int c4  = (tid & 31) * 4;
  float m0 = ml[row],        l0 = ml[3072 + row];
  float m1 = ml[2*3072+row], l1 = ml[3*3072 + row];
  float m  = fmaxf(m0, m1);
  float e0 = __expf(m0 - m), e1 = __expf(m1 - m);
  float inv = __fdividef(1.f, l0*e0 + l1*e1);
  float4v v0 = *(const float4v*)(ctp0 + (size_t)row*H_ + c4);
  float4v v1 = *(const float4v*)(ctp1 + (size_t)row*H_ + c4);
  float4v r;
  r[0] = (v0[0]*e0 + v1[0]*e1)*inv;
  r[1] = (v0[1]*e0 + v1[1]*e1)*inv;
  r[2] = (v0[2]*e0 + v1[2]*e1)*inv;
  r[3] = (v0[3]*e0 + v1[3]*e1)*inv;
  *(float4v*)(ct + (size_t)row*H_ + c4) = r;
}

// LSTM scan — round-5 body (measured 180-183 µs; best so far). Untouched.
__global__ __launch_bounds__(512) void lstm_kernel(
    const float* __restrict__ gx, const float* __restrict__ Whh,
    float* __restrict__ out)
{
  __shared__ __align__(16) unsigned short h_s[2][128];
  const int tid  = threadIdx.x;
  const int b    = blockIdx.x;
  const int w    = tid >> 6;
  const int l    = tid & 63;
  const int col  = l & 15;
  const int quad = l >> 4;

  short8 bf[4][4];
  #pragma unroll
  for (int nt = 0; nt < 4; ++nt) {
    const int n = nt*128 + w*16 + col;
    #pragma unroll
    for (int kt = 0; kt < 4; ++kt) {
      const int k0 = kt*32 + quad*8;
      const float* src = Whh + (size_t)n*H_ + k0;
      float4v f0 = *(const float4v*)(src);
      float4v f1 = *(const float4v*)(src + 4);
      short8 v;
      v[0]=(short)f2bf(f0[0]); v[1]=(short)f2bf(f0[1]); v[2]=(short)f2bf(f0[2]); v[3]=(short)f2bf(f0[3]);
      v[4]=(short)f2bf(f1[0]); v[5]=(short)f2bf(f1[1]); v[6]=(short)f2bf(f1[2]); v[7]=(short)f2bf(f1[3]);
      bf[nt][kt] = v;
    }
  }

  if (tid < 128) { h_s[0][tid] = 0; h_s[1][tid] = 0; }
  float cst = 0.f;
  const int goff = w*16 + col;
  const float* gbase = gx + (size_t)b*L_*512 + goff*4;
  float* outp = out + (size_t)b*L_*H_ + goff;
  float4v gbuf[4];
  #pragma unroll
  for (int s = 0; s < 4; ++s)
    gbuf[s] = *(const float4v*)(gbase + (size_t)s*512);
  const float4v z4 = {0.f,0.f,0.f,0.f};
  const float NL2E = -1.4426950408889634f;   // -log2(e)
  const float P2L2E = 2.8853900817779268f;   //  2*log2(e)
  __syncthreads();

  for (int t4 = 0; t4 < L_; t4 += 4) {
    #pragma unroll
    for (int s = 0; s < 4; ++s) {
      const int tstep = t4 + s;
      const unsigned short* hb = h_s[s & 1];
      short8 a[4];
      #pragma unroll
      for (int kt=0;kt<4;++kt) a[kt] = *(const short8*)&hb[kt*32 + quad*8];
      float4v c0 = z4, c1 = z4, c2 = z4, c3 = z4;
      #pragma unroll
      for (int kt=0;kt<4;++kt) {
        c0 = __builtin_amdgcn_mfma_f32_16x16x32_bf16(a[kt], bf[0][kt], c0, 0,0,0);
        c1 = __builtin_amdgcn_mfma_f32_16x16x32_bf16(a[kt], bf[1][kt], c1, 0,0,0);
        c2 = __builtin_amdgcn_mfma_f32_16x16x32_bf16(a[kt], bf[2][kt], c2, 0,0,0);
        c3 = __builtin_amdgcn_mfma_f32_16x16x32_bf16(a[kt], bf[3][kt], c3, 0,0,0);
      }
      float g0 = c0[0] + gbuf[s][0];
      float g1 = c1[0] + gbuf[s][1];
      float g2 = c2[0] + gbuf[s][2];
      float g3 = c3[0] + gbuf[s][3];
      if (tstep + 4 < L_)
        gbuf[s] = *(const float4v*)(gbase + (size_t)(tstep+4)*512);
      if (quad == 0) {
        float ig = __builtin_amdgcn_rcpf(1.f + __builtin_amdgcn_exp2f(NL2E*g0));
        float fg = __builtin_amdgcn_rcpf(1.f + __builtin_amdgcn_exp2f(NL2E*g1));
        float gg = 1.f - 2.f*__builtin_amdgcn_rcpf(__builtin_amdgcn_exp2f(P2L2E*g2) + 1.f);
        float og = __builtin_amdgcn_rcpf(1.f + __builtin_amdgcn_exp2f(NL2E*g3));
        cst = fg*cst + ig*gg;
        float hn = og * (1.f - 2.f*__builtin_amdgcn_rcpf(__builtin_amdgcn_exp2f(P2L2E*cst) + 1.f));
        outp[(size_t)tstep*H_] = hn;
        h_s[(s+1)&1][goff] = f2bf(hn);
      }
      barrier_lds();
    }
  }
}

extern "C" void kernel_launch(void* const* d_in, const int* in_sizes, int n_in,
                              void* d_out, int out_size, void* d_ws, size_t ws_size,
                              hipStream_t stream)
{
  (void)in_sizes; (void)n_in; (void)out_size; (void)ws_size;
  const float* x     = (const float*)d_in[0];
  const unsigned char* xm = (const unsigned char*)d_in[1];
  const float* y     = (const float*)d_in[2];
  const unsigned char* ym = (const unsigned char*)d_in[3];
  const float* Wq_w  = (const float*)d_in[4];
  const float* Wq_b  = (const float*)d_in[5];
  const float* Wup_w = (const float*)d_in[6];
  const float* Wup_b = (const float*)d_in[7];
  const float* Wvp_b = (const float*)d_in[9];
  const float* V_w   = (const float*)d_in[10];
  const float* V_b   = (const float*)d_in[11];
  const float* Wg_w  = (const float*)d_in[12];
  const float* Wg_b  = (const float*)d_in[13];
  const float* W_ih  = (const float*)d_in[14];
  const float* W_hh  = (const float*)d_in[15];
  const float* b_ih  = (const float*)d_in[16];
  const float* b_hh  = (const float*)d_in[17];
  float* out = (float*)d_out;

  float* wsf    = (float*)d_ws;
  float* xp_ws  = wsf;                   // [3072][128]
  float* yp_ws  = xp_ws + 393216;        // [3072][128]
  float* ct_ws  = yp_ws + 393216;        // [3072][128] (merged ct)
  float* li_ws  = ct_ws + 393216;        // [3072][256]
  float* gx_ws  = li_ws + 786432;        // [3072][512] gate-interleaved
  float* ct2_ws = gx_ws + 1572864;       // [3072][128] (half-1 partial)
  float* ml_ws  = ct2_ws + 393216;       // [4][3072]  (m0,l0,m1,l1)

  proj_mfma_kernel<<<dim3(384),256,0,stream>>>(x, y, Wup_w, Wup_b, Wq_w, Wq_b, Wvp_b, xp_ws, yp_ws);
  // half-0 partial goes into ct_ws, half-1 into ct2_ws; merge overwrites ct_ws
  attn_kernel<<<dim3(48,8,2),256,0,stream>>>(xp_ws, yp_ws, y, xm, ym, V_w, V_b, ct_ws, ct2_ws, ml_ws);
  attn_merge_kernel<<<dim3(384),256,0,stream>>>(ct_ws, ct2_ws, ml_ws, ct_ws);
  mfma_rowgemm_kernel<256><<<dim3(96,4),256,0,stream>>>(x, ct_ws, Wg_w, Wg_b, nullptr, li_ws, 256, 2);
  mfma_rowgemm_kernel<256><<<dim3(96,8),256,0,stream>>>(li_ws, nullptr, W_ih, b_ih, b_hh, gx_ws, 512, 3);
  lstm_kernel<<<dim3(8),512,0,stream>>>(gx_ws, W_hh, out);
}